// Round 7
// baseline (1784.786 us; speedup 1.0000x reference)
//
#include <hip/hip_runtime.h>
#include <type_traits>
#include <utility>
#include <cstdint>

typedef unsigned short u16;
typedef __attribute__((ext_vector_type(4))) float f32x4;
typedef __attribute__((ext_vector_type(8))) short s16x8;
typedef __attribute__((ext_vector_type(8))) __bf16 b16x8;

// ---- MFMA operand-type hedge: builtin takes either short8 or __bf16x8 ----
template <typename T, typename = void> struct MfmaTakes : std::false_type {};
template <typename T>
struct MfmaTakes<T, std::void_t<decltype(__builtin_amdgcn_mfma_f32_16x16x32_bf16(
    std::declval<T>(), std::declval<T>(), std::declval<f32x4>(), 0, 0, 0))>>
    : std::true_type {};
using abvec = std::conditional_t<MfmaTakes<s16x8>::value, s16x8, b16x8>;
static_assert(sizeof(abvec) == 16, "frag must be 4 VGPRs");

template <typename T>
__device__ __forceinline__ f32x4 mfma_bf16(T a, T b, f32x4 c) {
  return __builtin_amdgcn_mfma_f32_16x16x32_bf16(a, b, c, 0, 0, 0);
}

__device__ __forceinline__ float b2f(u16 v) {
  union { unsigned u; float f; } x; x.u = ((unsigned)v) << 16; return x.f;
}
__device__ __forceinline__ u16 f2b(float f) {
  union { float f; unsigned u; } x; x.f = f;
  unsigned r = x.u + 0x7fffu + ((x.u >> 16) & 1u);
  return (u16)(r >> 16);
}

__device__ __forceinline__ void gld16(const void* g, void* l) {
  auto gp = reinterpret_cast<const __attribute__((address_space(1))) unsigned int*>(
      reinterpret_cast<uintptr_t>(g));
  auto lp = reinterpret_cast<__attribute__((address_space(3))) unsigned int*>(
      reinterpret_cast<uintptr_t>(l));
  __builtin_amdgcn_global_load_lds(gp, lp, 16, 0, 0);
}

#define NN 16384
#define NE 131072
#define NG 16

// ---------------- dtype detect: bf16 vs f32 input buffers ----------------
__global__ void detect_dtype(const u16* __restrict__ x, int* __restrict__ flag) {
  __shared__ int cnt;
  if (threadIdx.x == 0) cnt = 0;
  __syncthreads();
  int local = 0;
#pragma unroll
  for (int i = 0; i < 8; i++) {
    u16 h = x[threadIdx.x * 8 + i];
    int e = (h >> 7) & 0xFF;
    if (h == 0 || (e >= 110 && e <= 134)) local++;
  }
  atomicAdd(&cnt, local);
  __syncthreads();
  if (threadIdx.x == 0) *flag = (cnt >= 1700) ? 1 : 0;
}

// ---------------- batched convert of tensors to bf16 ----------------
struct CvtJob {
  const void* src[14];
  void* dst[14];
  int n[14];
};

__global__ __launch_bounds__(256) void cvt_all(CvtJob jb, const int* __restrict__ flag) {
  const int idx = blockIdx.x * 256 + threadIdx.x;
  const int f = *flag;
  int off = 0;
#pragma unroll
  for (int j = 0; j < 14; j++) {
    const int nn = jb.n[j];
    if (idx < off + nn) {
      const int i = idx - off;
      u16 v = f ? ((const u16*)jb.src[j])[i]
                : f2b(((const float*)jb.src[j])[i]);
      ((u16*)jb.dst[j])[i] = v;
      return;
    }
    off += nn;
  }
}

// -------- plain convert (row-major, no transpose) --------
__global__ __launch_bounds__(256) void cvt_plain(
    const void* __restrict__ src, u16* __restrict__ dst, int n,
    const int* __restrict__ flag)
{
  const int i = blockIdx.x * 256 + threadIdx.x;
  if (i >= n) return;
  dst[i] = *flag ? ((const u16*)src)[i] : f2b(((const float*)src)[i]);
}

// ---------------- GEMM: 128x128, BK=32, 3-slot ring, counted vmcnt ----------------
// rb != null: per-row bias rb[ridx[global_row]*rbs + col] added pre-activation
// (rank-16 u_r-column folding; ridx is L2-hot, nearly block-constant for sorted rows).
__global__ __launch_bounds__(256, 3) void gemm_bt(
    const u16* __restrict__ A, const u16* __restrict__ Bt,
    const u16* __restrict__ bias, u16* __restrict__ C,
    int M, int N, int K, int ldc, int relu,
    const u16* __restrict__ rb, const int* __restrict__ ridx, int rbs)
{
  __shared__ alignas(16) u16 smem[24576];  // 48KB: 3 slots x (A 4096 | B 4096) u16
  const int tid = threadIdx.x;
  const int wave = tid >> 6, lane = tid & 63;
  const int m0 = blockIdx.x * 128, n0 = blockIdx.y * 128;

  const int srow = lane >> 2;              // 0..15
  const int kslot = lane & 3;              // 16B slot within row's 64B
  const int sswz = (srow >> 1) & 3;        // row-based XOR swizzle
  const u16* gA = A + (size_t)(m0 + wave * 32 + srow) * K + (kslot ^ sswz) * 8;
  const u16* gB = Bt + (size_t)(n0 + wave * 32 + srow) * K + (kslot ^ sswz) * 8;
  const int loff = (wave * 32 + srow) * 32 + kslot * 8;  // == wave*2048B + lane*16B

  const int wm = (wave >> 1) * 64;
  const int wn = (wave & 1) * 64;
  const int fr = lane & 15;
  const int fks = ((lane >> 4) ^ ((fr >> 1) & 3)) * 8;   // swizzled read slot

  f32x4 acc[4][4] = {};
  const int NT = K >> 5;                   // BK=32 tiles

#define STAGE(t, s) do { \
    const int o_ = (t) * 32; \
    u16* S_ = smem + (s) * 8192; \
    gld16(gA + o_, S_ + loff); gld16(gA + 16 * (size_t)K + o_, S_ + loff + 512); \
    gld16(gB + o_, S_ + 4096 + loff); gld16(gB + 16 * (size_t)K + o_, S_ + 4096 + loff + 512); \
  } while (0)

  STAGE(0, 0);
  if (NT > 1) {
    STAGE(1, 1);
    __asm__ volatile("s_waitcnt vmcnt(4)" ::: "memory");
  } else {
    __asm__ volatile("s_waitcnt vmcnt(0)" ::: "memory");
  }
  __builtin_amdgcn_s_barrier();

  int sl = 0;                              // slot of tile t
  for (int t = 0; t < NT; t++) {
    if (t + 2 < NT) {
      const int sw = (sl + 2 >= 3) ? sl - 1 : sl + 2;   // slot of tile t+2
      STAGE(t + 2, sw);
    }
    const u16* As = smem + sl * 8192;
    const u16* Bs = As + 4096;
    abvec af[4], bf[4];
#pragma unroll
    for (int i = 0; i < 4; i++)
      af[i] = *(const abvec*)&As[(wm + i * 16 + fr) * 32 + fks];
#pragma unroll
    for (int i = 0; i < 4; i++)
      bf[i] = *(const abvec*)&Bs[(wn + i * 16 + fr) * 32 + fks];
    __builtin_amdgcn_s_setprio(1);
#pragma unroll
    for (int mi = 0; mi < 4; mi++)
#pragma unroll
      for (int ni = 0; ni < 4; ni++)
        acc[mi][ni] = mfma_bf16(af[mi], bf[ni], acc[mi][ni]);
    __builtin_amdgcn_s_setprio(0);
    if (t + 2 < NT) __asm__ volatile("s_waitcnt vmcnt(4)" ::: "memory");
    else            __asm__ volatile("s_waitcnt vmcnt(0)" ::: "memory");
    __builtin_amdgcn_s_barrier();
    sl = (sl == 2) ? 0 : sl + 1;
  }
#undef STAGE

  const int crow0 = (lane >> 4) * 4;
  float bv[4];
#pragma unroll
  for (int ni = 0; ni < 4; ni++) bv[ni] = b2f(bias[n0 + wn + ni * 16 + fr]);

  u16* W = smem + wave * 4096;             // private 64x64, col8 ^ (row&7) swizzle
#pragma unroll
  for (int mi = 0; mi < 4; mi++) {
#pragma unroll
    for (int ni = 0; ni < 4; ni++) {
      f32x4 v = acc[mi][ni];
      const int colx = ni * 16 + fr;
      const int cl = colx & 7, ch = colx >> 3;
#pragma unroll
      for (int r = 0; r < 4; r++) {
        const int rowx = mi * 16 + crow0 + r;
        float f = v[r] + bv[ni];
        if (rb) f += b2f(rb[(size_t)ridx[m0 + wm + rowx] * rbs + n0 + wn + ni * 16 + fr]);
        if (relu) f = fmaxf(f, 0.0f);
        W[rowx * 64 + ((ch ^ (rowx & 7)) << 3) + cl] = f2b(f);
      }
    }
  }
  __asm__ volatile("s_waitcnt lgkmcnt(0)" ::: "memory");
#pragma unroll
  for (int p = 0; p < 8; p++) {
    const int rowx = p * 8 + (lane >> 3);
    const int pc = lane & 7;
    const int lc = pc ^ (rowx & 7);
    s16x8 val = *(const s16x8*)&W[rowx * 64 + pc * 8];
    *(s16x8*)&C[(size_t)(m0 + wm + rowx) * ldc + n0 + wn + lc * 8] = val;
  }
}

// ---------------- GEMM 256x256, BK=32, 3-slot ring, 1024 threads ----------------
// Round-4 A/B winner; used for all N=1024 GEMMs. rb: per-row bias (see gemm_bt).
// Requires: M%256==0, N%256==0, K%32==0.
__global__ __launch_bounds__(1024) void gemm256b(
    const u16* __restrict__ A, const u16* __restrict__ Bt,
    const u16* __restrict__ bias, u16* __restrict__ C,
    int K, int ldc, int relu,
    const u16* __restrict__ rb, const int* __restrict__ ridx, int rbs)
{
  __shared__ alignas(16) u16 smem[49152];  // 96KB: 3 slots x (A 8192 | B 8192) u16
  const int tid = threadIdx.x;
  const int wave = tid >> 6, lane = tid & 63;
  const int wr = wave >> 2, wc = wave & 3;
  const int m0 = blockIdx.x << 8, n0 = blockIdx.y << 8;

  // staging: row = tid>>2 (0..255), phys 16B slot = tid&3, global slot XOR-swizzled
  const int srow = tid >> 2;
  const int kslot = tid & 3;
  const int sswz = (srow >> 1) & 3;
  const u16* gA = A  + (size_t)(m0 + srow) * K + (kslot ^ sswz) * 8;
  const u16* gB = Bt + (size_t)(n0 + srow) * K + (kslot ^ sswz) * 8;
  const int loff = tid * 8;                // u16; == srow*32 + kslot*8

  const int fr = lane & 15;
  const int fks = ((lane >> 4) ^ ((fr >> 1) & 3)) * 8;   // swizzled read slot
  const int aob = (wr * 64 + fr) * 32 + fks;             // + i*512
  const int bob = (wc * 64 + fr) * 32 + fks;             // + ni*512

  f32x4 acc[4][4] = {};
  const int NT = K >> 5;                   // BK=32 tiles

#define STAGE2(t, s) do { \
    const int o_ = (t) * 32; \
    u16* S_ = smem + (s) * 16384; \
    gld16(gA + o_, S_ + loff); gld16(gB + o_, S_ + 8192 + loff); \
  } while (0)

  STAGE2(0, 0);
  if (NT > 1) {
    STAGE2(1, 1);
    __asm__ volatile("s_waitcnt vmcnt(2)" ::: "memory");
  } else {
    __asm__ volatile("s_waitcnt vmcnt(0)" ::: "memory");
  }
  __builtin_amdgcn_s_barrier();

  int sl = 0;
  for (int t = 0; t < NT; t++) {
    if (t + 2 < NT) {
      const int sw = (sl + 2 >= 3) ? sl - 1 : sl + 2;
      STAGE2(t + 2, sw);
    }
    const u16* As = smem + sl * 16384;
    const u16* Bs = As + 8192;
    abvec af[4], bf[4];
#pragma unroll
    for (int i = 0; i < 4; i++)
      af[i] = *(const abvec*)&As[aob + i * 512];
#pragma unroll
    for (int i = 0; i < 4; i++)
      bf[i] = *(const abvec*)&Bs[bob + i * 512];
    __builtin_amdgcn_s_setprio(1);
#pragma unroll
    for (int mi = 0; mi < 4; mi++)
#pragma unroll
      for (int ni = 0; ni < 4; ni++)
        acc[mi][ni] = mfma_bf16(af[mi], bf[ni], acc[mi][ni]);
    __builtin_amdgcn_s_setprio(0);
    if (t + 2 < NT) __asm__ volatile("s_waitcnt vmcnt(2)" ::: "memory");
    else            __asm__ volatile("s_waitcnt vmcnt(0)" ::: "memory");
    __builtin_amdgcn_s_barrier();
    sl = (sl == 2) ? 0 : sl + 1;
  }
#undef STAGE2

  // epilogue: wave-private 64x32 half-tiles (4KB x 16 waves = 64KB), no barriers
  const int crow0 = (lane >> 4) * 4;
  float bv[4];
#pragma unroll
  for (int ni = 0; ni < 4; ni++) bv[ni] = b2f(bias[n0 + wc * 64 + ni * 16 + fr]);
  u16* W = smem + wave * 2048;             // 64 rows x 32 u16, col4 ^ (row&3) swizzle
#pragma unroll
  for (int h = 0; h < 2; h++) {
    if (h) __asm__ volatile("s_waitcnt lgkmcnt(0)" ::: "memory");
#pragma unroll
    for (int mi = 0; mi < 4; mi++) {
#pragma unroll
      for (int nh = 0; nh < 2; nh++) {
        const int ni = h * 2 + nh;
        f32x4 v = acc[mi][ni];
        const int colx = nh * 16 + fr;     // 0..31
        const int cl = colx & 7, ch = colx >> 3;   // ch 0..3
#pragma unroll
        for (int r = 0; r < 4; r++) {
          const int rowx = mi * 16 + crow0 + r;
          float f = v[r] + bv[ni];
          if (rb) f += b2f(rb[(size_t)ridx[m0 + wr * 64 + rowx] * rbs + n0 + wc * 64 + ni * 16 + fr]);
          if (relu) f = fmaxf(f, 0.0f);
          W[rowx * 32 + ((ch ^ (rowx & 3)) << 3) + cl] = f2b(f);
        }
      }
    }
    __asm__ volatile("s_waitcnt lgkmcnt(0)" ::: "memory");
#pragma unroll
    for (int p = 0; p < 4; p++) {
      const int rowx = p * 16 + (lane >> 2);
      const int pc = lane & 3;
      const int lc = pc ^ (rowx & 3);
      s16x8 val = *(const s16x8*)&W[rowx * 32 + pc * 8];
      *(s16x8*)&C[(size_t)(m0 + wr * 64 + rowx) * ldc + n0 + wc * 64 + h * 32 + lc * 8] = val;
    }
  }
}

// -------- transpose + zero-pad + convert + optional K-permute; k0 = src row offset --------
__global__ __launch_bounds__(256) void transpose_pad(
    const void* __restrict__ src, u16* __restrict__ dst, int K, int N, int Kp,
    int perm, int k0, const int* __restrict__ flag)
{
  __shared__ u16 tile[32][33];
  const int f = *flag;
  const u16* s16p = (const u16*)src;
  const float* sfp = (const float*)src;
  const int kb = blockIdx.x * 32, nb = blockIdx.y * 32;
  const int tx = threadIdx.x & 31, ty = threadIdx.x >> 5;
#pragma unroll
  for (int i = 0; i < 32; i += 8) {
    int k = kb + ty + i, n = nb + tx;
    u16 v = 0;
    if (k < K && n < N)
      v = f ? s16p[(size_t)(k0 + k) * N + n] : f2b(sfp[(size_t)(k0 + k) * N + n]);
    tile[ty + i][tx] = v;
  }
  __syncthreads();
#pragma unroll
  for (int i = 0; i < 32; i += 8) {
    int n = nb + ty + i, k = kb + tx;
    if (n < N && k < Kp) {
      int nk = perm ? (k < 9 ? 512 + k : (k < 521 ? k - 9 : k)) : k;
      dst[(size_t)n * Kp + nk] = tile[tx][ty + i];
    }
  }
}

// -------- fused-tail: FUSEDT cols 1024..1055 = x-part of n1w0 (from N1W0T perm layout) --------
__global__ __launch_bounds__(256) void fuse_tail(
    const u16* __restrict__ n1w0t, u16* __restrict__ fused)
{
  const int idx = blockIdx.x * 256 + threadIdx.x;   // 512*32
  const int p = idx >> 5, t = idx & 31;
  fused[p * 1056 + 1024 + t] = n1w0t[p * 544 + 512 + t];  // cols 521..543 of N1W0T are 0
}

// -------- fused bias: FB[p] = n1b0[p] + sum_j e_bf[j] * n1w0_e[j][p] --------
__global__ __launch_bounds__(256) void fuse_bias(
    const u16* __restrict__ ebf, const u16* __restrict__ n1b0,
    const u16* __restrict__ n1w0e, u16* __restrict__ fb)
{
  const int p = blockIdx.x * 256 + threadIdx.x;     // 512
  float acc = b2f(n1b0[p]);
#pragma unroll 8
  for (int j = 0; j < 512; j++) acc += b2f(ebf[j]) * b2f(n1w0e[p * 512 + j]);
  fb[p] = f2b(acc);
}

// -------- rank-16 fold tables: UWB[g][n] = e_b0[n] + ur[g]·e_w0[19:275] --------
__global__ __launch_bounds__(256) void make_uwb(
    const void* __restrict__ w0, const u16* __restrict__ ur,
    const u16* __restrict__ eb0, u16* __restrict__ uwb,
    const int* __restrict__ flag)
{
  const int g = blockIdx.x;                // grid (16, 4)
  const int n = blockIdx.y * 256 + threadIdx.x;
  const int f = *flag;
  __shared__ u16 us[256];
  us[threadIdx.x] = ur[g * 256 + threadIdx.x];
  __syncthreads();
  float acc = b2f(eb0[n]);
  if (f) {
    const u16* wp = (const u16*)w0 + 19ull * 1024 + n;
#pragma unroll 8
    for (int j = 0; j < 256; j++) acc += b2f(us[j]) * b2f(wp[(size_t)j * 1024]);
  } else {
    const float* wp = (const float*)w0 + 19ull * 1024 + n;
#pragma unroll 8
    for (int j = 0; j < 256; j++) acc += b2f(us[j]) * wp[(size_t)j * 1024];
  }
  uwb[g * 1024 + n] = f2b(acc);
}

// -------- UW2[g][p] = n2b0[p] + ur[g]·n2w0[521:777] --------
__global__ __launch_bounds__(256) void make_uw2(
    const void* __restrict__ w, const u16* __restrict__ ur,
    const u16* __restrict__ b0, u16* __restrict__ uw2,
    const int* __restrict__ flag)
{
  const int g = blockIdx.x;                // grid (16, 2)
  const int p = blockIdx.y * 256 + threadIdx.x;
  const int f = *flag;
  __shared__ u16 us[256];
  us[threadIdx.x] = ur[g * 256 + threadIdx.x];
  __syncthreads();
  float acc = b2f(b0[p]);
  if (f) {
    const u16* wp = (const u16*)w + 521ull * 512 + p;
#pragma unroll 8
    for (int j = 0; j < 256; j++) acc += b2f(us[j]) * b2f(wp[(size_t)j * 512]);
  } else {
    const float* wp = (const float*)w + 521ull * 512 + p;
#pragma unroll 8
    for (int j = 0; j < 256; j++) acc += b2f(us[j]) * wp[(size_t)j * 512];
  }
  uw2[g * 512 + p] = f2b(acc);
}

// -------- dim_reduce K-split: grid (16 graphs, 8 k-tiles), partials into f32 --------
__global__ __launch_bounds__(256) void dim_reduce2(
    const u16* __restrict__ u, const void* __restrict__ w,
    float* __restrict__ uacc, const int* __restrict__ flag)
{
  const int g = blockIdx.x, kt = blockIdx.y, j = threadIdx.x;
  const int f = *flag;
  __shared__ u16 us[512];
  us[j] = u[g * 4096 + kt * 512 + j];
  us[256 + j] = u[g * 4096 + kt * 512 + 256 + j];
  __syncthreads();
  float acc = 0.0f;
  if (f) {
    const u16* wp = (const u16*)w + (size_t)(kt * 512) * 256 + j;
#pragma unroll 8
    for (int k = 0; k < 512; k++) acc += b2f(us[k]) * b2f(wp[(size_t)k * 256]);
  } else {
    const float* wp = (const float*)w + (size_t)(kt * 512) * 256 + j;
#pragma unroll 8
    for (int k = 0; k < 512; k++) acc += b2f(us[k]) * wp[(size_t)k * 256];
  }
  atomicAdd(&uacc[g * 256 + j], acc);
}

__global__ __launch_bounds__(256) void finish_ur(
    const float* __restrict__ uacc, const u16* __restrict__ bdr,
    u16* __restrict__ ur)
{
  const int i = blockIdx.x * 256 + threadIdx.x;  // 4096
  ur[i] = f2b(uacc[i] + b2f(bdr[i & 255]));
}

// -------- edge sort by row: count -> prefix -> perm --------
__global__ __launch_bounds__(256) void count_edges(
    const int* __restrict__ row, int* __restrict__ cnt)
{
  const int e = blockIdx.x * 256 + threadIdx.x;
  if (e < NE) atomicAdd(&cnt[row[e]], 1);
}

__global__ __launch_bounds__(256) void prefix_offs(
    const int* __restrict__ cnt, int* __restrict__ offs, int* __restrict__ cursor)
{
  __shared__ int part[256];
  __shared__ int base[256];
  const int t = threadIdx.x;
  int s = 0;
#pragma unroll
  for (int i = 0; i < 64; i++) s += cnt[t * 64 + i];
  part[t] = s;
  __syncthreads();
  if (t == 0) {
    int r = 0;
    for (int i = 0; i < 256; i++) { base[i] = r; r += part[i]; }
  }
  __syncthreads();
  int r = base[t];
#pragma unroll
  for (int i = 0; i < 64; i++) {
    const int n = t * 64 + i;
    offs[n] = r; cursor[n] = r; r += cnt[n];
  }
  if (t == 255) offs[16384] = r;   // == NE
}

__global__ __launch_bounds__(256) void build_perm(
    const int* __restrict__ row, int* __restrict__ cursor, int* __restrict__ eperm)
{
  const int e = blockIdx.x * 256 + threadIdx.x;
  const int pos = atomicAdd(&cursor[row[e]], 1);
  eperm[pos] = e;
}

// -------- edge input gather (sorted order), stride 32: [x_r(9)|x_c(9)|ea(1)|0] + bidx --------
__global__ __launch_bounds__(256) void build_ein2(
    const u16* __restrict__ x, const u16* __restrict__ ea,
    const int* __restrict__ row, const int* __restrict__ col,
    const int* __restrict__ batch, const int* __restrict__ eperm,
    u16* __restrict__ out, int* __restrict__ bidx, int e0)
{
  const int idx = blockIdx.x * 256 + threadIdx.x;   // echunk*4
  const int le = idx >> 2, g = idx & 3;
  const int c0 = g * 8;
  const int e = eperm[e0 + le];
  const int r = row[e];
  const int cl = col[e];
  if (g == 0) bidx[le] = batch[r];
  alignas(16) u16 v[8];
#pragma unroll
  for (int j = 0; j < 8; j++) {
    const int c = c0 + j;
    u16 t;
    if (c < 9)        t = x[r * 9 + c];
    else if (c < 18)  t = x[cl * 9 + (c - 9)];
    else if (c == 18) t = ea[e];
    else              t = 0;
    v[j] = t;
  }
  *(s16x8*)&out[(size_t)le * 32 + c0] = *(const s16x8*)v;
}

// -------- fill h-tail cols 1024..1055 with x[col] (stride 1056) --------
__global__ __launch_bounds__(256) void fill_h_tail(
    const u16* __restrict__ x, const int* __restrict__ col,
    const int* __restrict__ eperm, u16* __restrict__ out, int e0)
{
  const int idx = blockIdx.x * 256 + threadIdx.x;   // echunk*4
  const int le = idx >> 2, j8 = idx & 3;
  const int c0 = 1024 + j8 * 8;
  const int cl = col[eperm[e0 + le]];
  alignas(16) u16 v[8];
#pragma unroll
  for (int j = 0; j < 8; j++) {
    const int c = c0 + j;
    v[j] = (c < 1033) ? x[cl * 9 + (c - 1024)] : (u16)0;
  }
  *(s16x8*)&out[(size_t)le * 1056 + c0] = *(const s16x8*)v;
}

// -------- segment reduce (sorted rows; first-touch WRITES -> no AGG memset) --------
__global__ __launch_bounds__(256) void seg_reduce(
    const u16* __restrict__ h, const int* __restrict__ offs,
    float* __restrict__ agg, int e0, int echunk)
{
  const int wave = threadIdx.x >> 6, lane = threadIdx.x & 63;
  const int n = blockIdx.x * 4 + wave;
  int lo = offs[n], hi = offs[n + 1];
  const int first = (lo >= e0);            // segment's first edge is in this chunk
  lo = lo > e0 ? lo : e0;
  const int e1 = e0 + echunk;
  hi = hi < e1 ? hi : e1;
  if (lo >= hi) return;
  const int c0 = lane * 8;
  float acc[8] = {};
  for (int i = lo; i < hi; i++) {
    s16x8 v = *(const s16x8*)&h[(size_t)(i - e0) * 512 + c0];
#pragma unroll
    for (int j = 0; j < 8; j++) acc[j] += b2f((u16)v[j]);
  }
  float* ap = &agg[(size_t)n * 512 + c0];
  if (first) {
#pragma unroll
    for (int j = 0; j < 8; j++) ap[j] = acc[j];
  } else {
#pragma unroll
    for (int j = 0; j < 8; j++) ap[j] += acc[j];
  }
}

// -------- nin2 build: [agg/cnt(512) | x(9) | pad(23)] stride 544 (ur folded into UW2) --------
__global__ __launch_bounds__(256) void build_nin2(
    const u16* __restrict__ x, const float* __restrict__ agg,
    const int* __restrict__ cnt, u16* __restrict__ out, int n0)
{
  const int idx = blockIdx.x * 256 + threadIdx.x;   // nodch*68
  const int le = idx / 68, g = idx % 68;
  const int c0 = g * 8;
  const int n = n0 + le;
  alignas(16) u16 v[8];
  if (c0 < 512) {
    const int cn = cnt[n];
    if (cn == 0) {
#pragma unroll
      for (int j = 0; j < 8; j++) v[j] = 0;
    } else {
      const float den = (float)cn;
      const f32x4* ap = (const f32x4*)&agg[(size_t)n * 512 + c0];
      f32x4 a0 = ap[0], a1 = ap[1];
#pragma unroll
      for (int j = 0; j < 4; j++) { v[j] = f2b(a0[j] / den); v[4 + j] = f2b(a1[j] / den); }
    }
  } else {
#pragma unroll
    for (int j = 0; j < 8; j++) {
      const int c = c0 + j;
      v[j] = (c < 521) ? x[n * 9 + (c - 512)] : (u16)0;
    }
  }
  *(s16x8*)&out[(size_t)le * 544 + c0] = *(const s16x8*)v;
}

// -------- final: out[n0+n] = h[n,:] . w + b --------
__global__ __launch_bounds__(256) void final_dot(
    const u16* __restrict__ h, const u16* __restrict__ w,
    const u16* __restrict__ b, void* __restrict__ out, int n0,
    const int* __restrict__ flag)
{
  const int wave = threadIdx.x >> 6, lane = threadIdx.x & 63;
  const int n = blockIdx.x * 4 + wave;
  const u16* hp = h + (size_t)n * 512 + lane * 8;
  const u16* wp = w + lane * 8;
  float s = 0.0f;
#pragma unroll
  for (int i = 0; i < 8; i++) s += b2f(hp[i]) * b2f(wp[i]);
#pragma unroll
  for (int off = 32; off > 0; off >>= 1) s += __shfl_down(s, off, 64);
  if (lane == 0) {
    float r = s + b2f(b[0]);
    if (*flag) ((u16*)out)[n0 + n] = f2b(r);
    else       ((float*)out)[n0 + n] = r;
  }
}

// ---------------- workspace layout (static part) ----------------
constexpr size_t OFF_FLAG = 0;
constexpr size_t OFF_XC   = 64;
constexpr size_t OFF_EAC  = OFF_XC   + 147456ull * 2;
constexpr size_t OFF_UC   = OFF_EAC  + 131072ull * 2;
constexpr size_t OFF_BDR  = OFF_UC   + 65536ull * 2;
constexpr size_t OFF_EB0  = OFF_BDR  + 256ull * 2;
constexpr size_t OFF_EB1  = OFF_EB0  + 1024ull * 2;
constexpr size_t OFF_EB2  = OFF_EB1  + 1024ull * 2;
constexpr size_t OFF_EB3  = OFF_EB2  + 1024ull * 2;
constexpr size_t OFF_EBF  = OFF_EB3  + 1024ull * 2;
constexpr size_t OFF_N1B0 = OFF_EBF  + 512ull * 2;
constexpr size_t OFF_N1B1 = OFF_N1B0 + 512ull * 2;
constexpr size_t OFF_N2B0 = OFF_N1B1 + 512ull * 2;
constexpr size_t OFF_N2W1 = OFF_N2B0 + 512ull * 2;
constexpr size_t OFF_N2B1 = OFF_N2W1 + 512ull * 2;
constexpr size_t OFF_OFFS = (OFF_N2B1 + 64 + 63) & ~63ull;     // 16385 int
constexpr size_t OFF_CUR  = OFF_OFFS + 16388ull * 4;           // 16384 int
constexpr size_t OFF_UACC = OFF_CUR  + 16384ull * 4;           // 4096 f32
static_assert(OFF_UACC + 4096 * 4 < (1ull << 20), "params+small fit in 1MB");

constexpr size_t OFF_W0T  = 1ull << 20;                        // now 1024x32
constexpr size_t OFF_W1T  = OFF_W0T  + 1024ull * 320 * 2;      // (slot kept sized for old 320)
constexpr size_t OFF_W2T  = OFF_W1T  + 1024ull * 1024 * 2;
constexpr size_t OFF_W3T  = OFF_W2T  + 1024ull * 1024 * 2;
constexpr size_t OFF_WFC  = OFF_W3T  + 1024ull * 1024 * 2;     // e_wf bf16 row-major 1024x512
constexpr size_t OFF_N1W0 = OFF_WFC  + 1024ull * 512 * 2;
constexpr size_t OFF_N1W1 = OFF_N1W0 + 512ull * 544 * 2;
constexpr size_t OFF_N2W0 = OFF_N1W1 + 512ull * 512 * 2;       // now 512x544
constexpr size_t OFF_N1WE = OFF_N2W0 + 512ull * 800 * 2;
constexpr size_t OFF_FUSE = OFF_N1WE + 512ull * 512 * 2;       // fused Bt 512x1056
constexpr size_t OFF_FB   = OFF_FUSE + 512ull * 1056 * 2;      // fused bias 512
constexpr size_t OFF_ZB   = OFF_FB   + 512ull * 2;             // zero bias 1024
constexpr size_t OFF_UWB  = OFF_ZB   + 1024ull * 2;            // 16x1024 fold table
constexpr size_t OFF_UW2  = OFF_UWB  + 16384ull * 2;           // 16x512 fold table
constexpr size_t OFF_UR   = OFF_UW2  + 8192ull * 2;
constexpr size_t OFF_CNT  = OFF_UR   + 16ull * 256 * 2;
constexpr size_t OFF_AGG  = OFF_CNT  + 16384ull * 4;
constexpr size_t OFF_BUF0 = OFF_AGG  + 16384ull * 512 * 4;   // dynamic from here

extern "C" void kernel_launch(void* const* d_in, const int* in_sizes, int n_in,
                              void* d_out, int out_size, void* d_ws, size_t ws_size,
                              hipStream_t stream) {
  const void* x_r  = d_in[0];
  const void* ea_r = d_in[1];
  const void* u_r  = d_in[2];
  const int*  ei    = (const int*)d_in[3];
  const int*  batch = (const int*)d_in[4];
  const void* w_dr = d_in[5];
  const void* b_dr = d_in[6];
  const void* e_w0 = d_in[7];  const void* e_b0 = d_in[8];
  const void* e_w1 = d_in[9];  const void* e_b1 = d_in[10];
  const void* e_w2 = d_in[11]; const void* e_b2 = d_in[12];
  const void* e_w3 = d_in[13]; const void* e_b3 = d_in[14];
  const void* e_wf = d_in[15]; const void* e_bf = d_in[16];
  const void* n1w0 = d_in[17]; const void* n1b0 = d_in[18];
  const void* n1w1 = d_in[19]; const void* n1b1 = d_in[20];
  const void* n2w0 = d_in[21]; const void* n2b0 = d_in[22];
  const void* n2w1 = d_in[23]; const void* n2b1 = d_in[24];

  const int* row = ei;
  const int* col = ei + NE;

  char* ws = (char*)d_ws;
  int*   FLAG = (int*)(ws + OFF_FLAG);
  u16*   XC   = (u16*)(ws + OFF_XC);
  u16*   EAC  = (u16*)(ws + OFF_EAC);
  u16*   UC   = (u16*)(ws + OFF_UC);
  u16*   BDRC = (u16*)(ws + OFF_BDR);
  u16*   EB0C = (u16*)(ws + OFF_EB0);
  u16*   EB1C = (u16*)(ws + OFF_EB1);
  u16*   EB2C = (u16*)(ws + OFF_EB2);
  u16*   EB3C = (u16*)(ws + OFF_EB3);
  u16*   EBFC = (u16*)(ws + OFF_EBF);
  u16*   N1B0C= (u16*)(ws + OFF_N1B0);
  u16*   N1B1C= (u16*)(ws + OFF_N1B1);
  u16*   N2B0C= (u16*)(ws + OFF_N2B0);
  u16*   N2W1C= (u16*)(ws + OFF_N2W1);
  u16*   N2B1C= (u16*)(ws + OFF_N2B1);
  int*   OFFS = (int*)(ws + OFF_OFFS);
  int*   CUR  = (int*)(ws + OFF_CUR);
  float* UACC = (float*)(ws + OFF_UACC);
  u16*   W0T  = (u16*)(ws + OFF_W0T);
  u16*   W1T  = (u16*)(ws + OFF_W1T);
  u16*   W2T  = (u16*)(ws + OFF_W2T);
  u16*   W3T  = (u16*)(ws + OFF_W3T);
  u16*   WFC  = (u16*)(ws + OFF_WFC);
  u16*   N1W0T= (u16*)(ws + OFF_N1W0);
  u16*   N1W1T= (u16*)(ws + OFF_N1W1);
  u16*   N2W0T= (u16*)(ws + OFF_N2W0);
  u16*   N1WE = (u16*)(ws + OFF_N1WE);
  u16*   FUSED= (u16*)(ws + OFF_FUSE);
  u16*   FB   = (u16*)(ws + OFF_FB);
  u16*   ZB   = (u16*)(ws + OFF_ZB);
  u16*   UWB  = (u16*)(ws + OFF_UWB);
  u16*   UW2  = (u16*)(ws + OFF_UW2);
  u16*   UR   = (u16*)(ws + OFF_UR);
  int*   CNT  = (int*)(ws + OFF_CNT);
  float* AGG  = (float*)(ws + OFF_AGG);
  (void)in_sizes; (void)n_in; (void)out_size;

  // dynamic sizing: P,Q at 1056-u16 (2112B) row stride + perm ints + bidx ints
  int echunk = 16384;
  while (echunk > 2048 &&
         OFF_BUF0 + (size_t)echunk * 4228 + (size_t)NE * 4 > ws_size) echunk >>= 1;
  u16* P    = (u16*)(ws + OFF_BUF0);
  u16* Q    = (u16*)(ws + OFF_BUF0 + (size_t)echunk * 2112);
  int* EPRM = (int*)(ws + OFF_BUF0 + (size_t)echunk * 4224);
  int* BIDX = EPRM + NE;
  const int nchunks = NE / echunk;
  const int nodch = echunk < NN ? echunk : NN;
  const int nodchn = NN / nodch;

  detect_dtype<<<1, 256, 0, stream>>>((const u16*)x_r, FLAG);

  CvtJob jb;
  const void* srcs[14] = {x_r, ea_r, u_r, b_dr, e_b0, e_b1, e_b2, e_b3,
                          e_bf, n1b0, n1b1, n2b0, n2w1, n2b1};
  void* dsts[14] = {XC, EAC, UC, BDRC, EB0C, EB1C, EB2C, EB3C,
                    EBFC, N1B0C, N1B1C, N2B0C, N2W1C, N2B1C};
  const int ns[14] = {147456, 131072, 65536, 256, 1024, 1024, 1024, 1024,
                      512, 512, 512, 512, 512, 1};
  int tot = 0;
  for (int j = 0; j < 14; j++) { jb.src[j] = srcs[j]; jb.dst[j] = dsts[j]; jb.n[j] = ns[j]; tot += ns[j]; }
  cvt_all<<<(tot + 255) / 256, 256, 0, stream>>>(jb, FLAG);

  transpose_pad<<<dim3(1, 32),  256, 0, stream>>>(e_w0, W0T,   19, 1024, 32, 0, 0, FLAG);
  transpose_pad<<<dim3(32, 32), 256, 0, stream>>>(e_w1, W1T, 1024, 1024, 1024, 0, 0, FLAG);
  transpose_pad<<<dim3(32, 32), 256, 0, stream>>>(e_w2, W2T, 1024, 1024, 1024, 0, 0, FLAG);
  transpose_pad<<<dim3(32, 32), 256, 0, stream>>>(e_w3, W3T, 1024, 1024, 1024, 0, 0, FLAG);
  transpose_pad<<<dim3(17, 16), 256, 0, stream>>>(n1w0, N1W0T, 521, 512, 544, 1, 0, FLAG);
  transpose_pad<<<dim3(16, 16), 256, 0, stream>>>(n1w1, N1W1T, 512, 512, 512, 0, 0, FLAG);
  transpose_pad<<<dim3(17, 16), 256, 0, stream>>>(n2w0, N2W0T, 521, 512, 544, 1, 0, FLAG);
  // fused-weight prep: N1WE[p*512+j] = n1w0[9+j][p]; WFC = e_wf row-major bf16
  transpose_pad<<<dim3(16, 16), 256, 0, stream>>>(n1w0, N1WE, 512, 512, 512, 0, 9, FLAG);
  cvt_plain<<<2048, 256, 0, stream>>>(e_wf, WFC, 1024 * 512, FLAG);

  (void)hipMemsetAsync(UACC, 0, 4096ull * 4, stream);
  (void)hipMemsetAsync(CNT, 0, 16384ull * 4, stream);
  (void)hipMemsetAsync(ZB, 0, 2048, stream);

  // FUSED[p*1056 + k] = sum_j n1w0[9+j][p] * e_wf[k][j]  (k<1024); tail = x-part
  gemm_bt<<<dim3(4, 8), 256, 0, stream>>>(N1WE, WFC, ZB, FUSED, 512, 1024, 512, 1056, 0,
                                          nullptr, nullptr, 0);
  fuse_tail<<<64, 256, 0, stream>>>(N1W0T, FUSED);
  fuse_bias<<<2, 256, 0, stream>>>(EBFC, N1B0C, N1WE, FB);

  dim_reduce2<<<dim3(NG, 8), 256, 0, stream>>>(UC, w_dr, UACC, FLAG);
  finish_ur<<<16, 256, 0, stream>>>(UACC, BDRC, UR);
  make_uwb<<<dim3(16, 4), 256, 0, stream>>>(e_w0, UR, EB0C, UWB, FLAG);
  make_uw2<<<dim3(16, 2), 256, 0, stream>>>(n2w0, UR, N2B0C, UW2, FLAG);

  count_edges<<<NE / 256, 256, 0, stream>>>(row, CNT);
  prefix_offs<<<1, 256, 0, stream>>>(CNT, OFFS, CUR);
  build_perm<<<NE / 256, 256, 0, stream>>>(row, CUR, EPRM);

  for (int c = 0; c < nchunks; c++) {
    const int e0 = c * echunk;
    build_ein2<<<echunk * 4 / 256, 256, 0, stream>>>(XC, EAC, row, col, batch, EPRM, P, BIDX, e0);
    gemm256b<<<dim3(echunk / 256, 4), 1024, 0, stream>>>(P, W0T, ZB, Q, 32, 1024, 1,
                                                         UWB, BIDX, 1024);
    gemm256b<<<dim3(echunk / 256, 4), 1024, 0, stream>>>(Q, W1T, EB1C, P, 1024, 1024, 1,
                                                         nullptr, nullptr, 0);
    gemm256b<<<dim3(echunk / 256, 4), 1024, 0, stream>>>(P, W2T, EB2C, Q, 1024, 1024, 1,
                                                         nullptr, nullptr, 0);
    gemm256b<<<dim3(echunk / 256, 4), 1024, 0, stream>>>(Q, W3T, EB3C, P, 1024, 1056, 1,
                                                         nullptr, nullptr, 0);
    fill_h_tail<<<echunk * 4 / 256, 256, 0, stream>>>(XC, col, EPRM, P, e0);
    gemm_bt<<<dim3(echunk / 128, 4), 256, 0, stream>>>(P, FUSED, FB, Q, echunk, 512, 1056, 512, 1,
                                                       nullptr, nullptr, 0);
    gemm_bt<<<dim3(echunk / 128, 4), 256, 0, stream>>>(Q, N1W1T, N1B1C, P, echunk, 512, 512, 512, 1,
                                                       nullptr, nullptr, 0);
    seg_reduce<<<NN / 4, 256, 0, stream>>>(P, OFFS, AGG, e0, echunk);
  }

  for (int c = 0; c < nodchn; c++) {
    const int n0 = c * nodch;
    build_nin2<<<nodch * 68 / 256, 256, 0, stream>>>(XC, AGG, CNT, P, n0);
    gemm_bt<<<dim3(nodch / 128, 4), 256, 0, stream>>>(P, N2W0T, ZB, Q, nodch, 512, 544, 512, 1,
                                                      UW2, batch + n0, 512);
    final_dot<<<nodch / 4, 256, 0, stream>>>(Q, N2W1C, N2B1C, d_out, n0, FLAG);
  }
}

// Round 8
// 1673.467 us; speedup vs baseline: 1.0665x; 1.0665x over previous
//
#include <hip/hip_runtime.h>
#include <type_traits>
#include <utility>
#include <cstdint>

typedef unsigned short u16;
typedef __attribute__((ext_vector_type(4))) float f32x4;
typedef __attribute__((ext_vector_type(8))) short s16x8;
typedef __attribute__((ext_vector_type(8))) __bf16 b16x8;

// ---- MFMA operand-type hedge: builtin takes either short8 or __bf16x8 ----
template <typename T, typename = void> struct MfmaTakes : std::false_type {};
template <typename T>
struct MfmaTakes<T, std::void_t<decltype(__builtin_amdgcn_mfma_f32_16x16x32_bf16(
    std::declval<T>(), std::declval<T>(), std::declval<f32x4>(), 0, 0, 0))>>
    : std::true_type {};
using abvec = std::conditional_t<MfmaTakes<s16x8>::value, s16x8, b16x8>;
static_assert(sizeof(abvec) == 16, "frag must be 4 VGPRs");

template <typename T>
__device__ __forceinline__ f32x4 mfma_bf16(T a, T b, f32x4 c) {
  return __builtin_amdgcn_mfma_f32_16x16x32_bf16(a, b, c, 0, 0, 0);
}

__device__ __forceinline__ float b2f(u16 v) {
  union { unsigned u; float f; } x; x.u = ((unsigned)v) << 16; return x.f;
}
__device__ __forceinline__ u16 f2b(float f) {
  union { float f; unsigned u; } x; x.f = f;
  unsigned r = x.u + 0x7fffu + ((x.u >> 16) & 1u);
  return (u16)(r >> 16);
}

__device__ __forceinline__ void gld16(const void* g, void* l) {
  auto gp = reinterpret_cast<const __attribute__((address_space(1))) unsigned int*>(
      reinterpret_cast<uintptr_t>(g));
  auto lp = reinterpret_cast<__attribute__((address_space(3))) unsigned int*>(
      reinterpret_cast<uintptr_t>(l));
  __builtin_amdgcn_global_load_lds(gp, lp, 16, 0, 0);
}

#define NN 16384
#define NE 131072
#define NG 16

// ---------------- dtype detect: bf16 vs f32 input buffers ----------------
__global__ void detect_dtype(const u16* __restrict__ x, int* __restrict__ flag) {
  __shared__ int cnt;
  if (threadIdx.x == 0) cnt = 0;
  __syncthreads();
  int local = 0;
#pragma unroll
  for (int i = 0; i < 8; i++) {
    u16 h = x[threadIdx.x * 8 + i];
    int e = (h >> 7) & 0xFF;
    if (h == 0 || (e >= 110 && e <= 134)) local++;
  }
  atomicAdd(&cnt, local);
  __syncthreads();
  if (threadIdx.x == 0) *flag = (cnt >= 1700) ? 1 : 0;
}

// ---------------- batched convert of tensors to bf16 ----------------
struct CvtJob {
  const void* src[14];
  void* dst[14];
  int n[14];
};

__global__ __launch_bounds__(256) void cvt_all(CvtJob jb, const int* __restrict__ flag) {
  const int idx = blockIdx.x * 256 + threadIdx.x;
  const int f = *flag;
  int off = 0;
#pragma unroll
  for (int j = 0; j < 14; j++) {
    const int nn = jb.n[j];
    if (idx < off + nn) {
      const int i = idx - off;
      u16 v = f ? ((const u16*)jb.src[j])[i]
                : f2b(((const float*)jb.src[j])[i]);
      ((u16*)jb.dst[j])[i] = v;
      return;
    }
    off += nn;
  }
}

// -------- plain convert (row-major, no transpose) --------
__global__ __launch_bounds__(256) void cvt_plain(
    const void* __restrict__ src, u16* __restrict__ dst, int n,
    const int* __restrict__ flag)
{
  const int i = blockIdx.x * 256 + threadIdx.x;
  if (i >= n) return;
  dst[i] = *flag ? ((const u16*)src)[i] : f2b(((const float*)src)[i]);
}

// ---------------- GEMM: 128x128, BK=32, 3-slot ring, counted vmcnt ----------------
// Round-6 EXACT body (no rb plumbing): keep hot-path codegen untouched.
__global__ __launch_bounds__(256, 3) void gemm_bt(
    const u16* __restrict__ A, const u16* __restrict__ Bt,
    const u16* __restrict__ bias, u16* __restrict__ C,
    int M, int N, int K, int ldc, int relu)
{
  __shared__ alignas(16) u16 smem[24576];  // 48KB: 3 slots x (A 4096 | B 4096) u16
  const int tid = threadIdx.x;
  const int wave = tid >> 6, lane = tid & 63;
  const int m0 = blockIdx.x * 128, n0 = blockIdx.y * 128;

  const int srow = lane >> 2;              // 0..15
  const int kslot = lane & 3;              // 16B slot within row's 64B
  const int sswz = (srow >> 1) & 3;        // row-based XOR swizzle
  const u16* gA = A + (size_t)(m0 + wave * 32 + srow) * K + (kslot ^ sswz) * 8;
  const u16* gB = Bt + (size_t)(n0 + wave * 32 + srow) * K + (kslot ^ sswz) * 8;
  const int loff = (wave * 32 + srow) * 32 + kslot * 8;  // == wave*2048B + lane*16B

  const int wm = (wave >> 1) * 64;
  const int wn = (wave & 1) * 64;
  const int fr = lane & 15;
  const int fks = ((lane >> 4) ^ ((fr >> 1) & 3)) * 8;   // swizzled read slot

  f32x4 acc[4][4] = {};
  const int NT = K >> 5;                   // BK=32 tiles

#define STAGE(t, s) do { \
    const int o_ = (t) * 32; \
    u16* S_ = smem + (s) * 8192; \
    gld16(gA + o_, S_ + loff); gld16(gA + 16 * (size_t)K + o_, S_ + loff + 512); \
    gld16(gB + o_, S_ + 4096 + loff); gld16(gB + 16 * (size_t)K + o_, S_ + 4096 + loff + 512); \
  } while (0)

  STAGE(0, 0);
  if (NT > 1) {
    STAGE(1, 1);
    __asm__ volatile("s_waitcnt vmcnt(4)" ::: "memory");
  } else {
    __asm__ volatile("s_waitcnt vmcnt(0)" ::: "memory");
  }
  __builtin_amdgcn_s_barrier();

  int sl = 0;                              // slot of tile t
  for (int t = 0; t < NT; t++) {
    if (t + 2 < NT) {
      const int sw = (sl + 2 >= 3) ? sl - 1 : sl + 2;   // slot of tile t+2
      STAGE(t + 2, sw);
    }
    const u16* As = smem + sl * 8192;
    const u16* Bs = As + 4096;
    abvec af[4], bf[4];
#pragma unroll
    for (int i = 0; i < 4; i++)
      af[i] = *(const abvec*)&As[(wm + i * 16 + fr) * 32 + fks];
#pragma unroll
    for (int i = 0; i < 4; i++)
      bf[i] = *(const abvec*)&Bs[(wn + i * 16 + fr) * 32 + fks];
    __builtin_amdgcn_s_setprio(1);
#pragma unroll
    for (int mi = 0; mi < 4; mi++)
#pragma unroll
      for (int ni = 0; ni < 4; ni++)
        acc[mi][ni] = mfma_bf16(af[mi], bf[ni], acc[mi][ni]);
    __builtin_amdgcn_s_setprio(0);
    if (t + 2 < NT) __asm__ volatile("s_waitcnt vmcnt(4)" ::: "memory");
    else            __asm__ volatile("s_waitcnt vmcnt(0)" ::: "memory");
    __builtin_amdgcn_s_barrier();
    sl = (sl == 2) ? 0 : sl + 1;
  }
#undef STAGE

  const int crow0 = (lane >> 4) * 4;
  float bv[4];
#pragma unroll
  for (int ni = 0; ni < 4; ni++) bv[ni] = b2f(bias[n0 + wn + ni * 16 + fr]);

  u16* W = smem + wave * 4096;             // private 64x64, col8 ^ (row&7) swizzle
#pragma unroll
  for (int mi = 0; mi < 4; mi++) {
#pragma unroll
    for (int ni = 0; ni < 4; ni++) {
      f32x4 v = acc[mi][ni];
      const int colx = ni * 16 + fr;
      const int cl = colx & 7, ch = colx >> 3;
#pragma unroll
      for (int r = 0; r < 4; r++) {
        const int rowx = mi * 16 + crow0 + r;
        float f = v[r] + bv[ni];
        if (relu) f = fmaxf(f, 0.0f);
        W[rowx * 64 + ((ch ^ (rowx & 7)) << 3) + cl] = f2b(f);
      }
    }
  }
  __asm__ volatile("s_waitcnt lgkmcnt(0)" ::: "memory");
#pragma unroll
  for (int p = 0; p < 8; p++) {
    const int rowx = p * 8 + (lane >> 3);
    const int pc = lane & 7;
    const int lc = pc ^ (rowx & 7);
    s16x8 val = *(const s16x8*)&W[rowx * 64 + pc * 8];
    *(s16x8*)&C[(size_t)(m0 + wm + rowx) * ldc + n0 + wn + lc * 8] = val;
  }
}

// ---------------- gemm_bt_rb: separate clone with per-row bias (N2W0 only) ----------------
__global__ __launch_bounds__(256, 3) void gemm_bt_rb(
    const u16* __restrict__ A, const u16* __restrict__ Bt,
    const u16* __restrict__ bias, u16* __restrict__ C,
    int M, int N, int K, int ldc, int relu,
    const u16* __restrict__ rb, const int* __restrict__ ridx, int rbs)
{
  __shared__ alignas(16) u16 smem[24576];
  const int tid = threadIdx.x;
  const int wave = tid >> 6, lane = tid & 63;
  const int m0 = blockIdx.x * 128, n0 = blockIdx.y * 128;

  const int srow = lane >> 2;
  const int kslot = lane & 3;
  const int sswz = (srow >> 1) & 3;
  const u16* gA = A + (size_t)(m0 + wave * 32 + srow) * K + (kslot ^ sswz) * 8;
  const u16* gB = Bt + (size_t)(n0 + wave * 32 + srow) * K + (kslot ^ sswz) * 8;
  const int loff = (wave * 32 + srow) * 32 + kslot * 8;

  const int wm = (wave >> 1) * 64;
  const int wn = (wave & 1) * 64;
  const int fr = lane & 15;
  const int fks = ((lane >> 4) ^ ((fr >> 1) & 3)) * 8;

  f32x4 acc[4][4] = {};
  const int NT = K >> 5;

#define STAGE(t, s) do { \
    const int o_ = (t) * 32; \
    u16* S_ = smem + (s) * 8192; \
    gld16(gA + o_, S_ + loff); gld16(gA + 16 * (size_t)K + o_, S_ + loff + 512); \
    gld16(gB + o_, S_ + 4096 + loff); gld16(gB + 16 * (size_t)K + o_, S_ + 4096 + loff + 512); \
  } while (0)

  STAGE(0, 0);
  if (NT > 1) {
    STAGE(1, 1);
    __asm__ volatile("s_waitcnt vmcnt(4)" ::: "memory");
  } else {
    __asm__ volatile("s_waitcnt vmcnt(0)" ::: "memory");
  }
  __builtin_amdgcn_s_barrier();

  int sl = 0;
  for (int t = 0; t < NT; t++) {
    if (t + 2 < NT) {
      const int sw = (sl + 2 >= 3) ? sl - 1 : sl + 2;
      STAGE(t + 2, sw);
    }
    const u16* As = smem + sl * 8192;
    const u16* Bs = As + 4096;
    abvec af[4], bf[4];
#pragma unroll
    for (int i = 0; i < 4; i++)
      af[i] = *(const abvec*)&As[(wm + i * 16 + fr) * 32 + fks];
#pragma unroll
    for (int i = 0; i < 4; i++)
      bf[i] = *(const abvec*)&Bs[(wn + i * 16 + fr) * 32 + fks];
    __builtin_amdgcn_s_setprio(1);
#pragma unroll
    for (int mi = 0; mi < 4; mi++)
#pragma unroll
      for (int ni = 0; ni < 4; ni++)
        acc[mi][ni] = mfma_bf16(af[mi], bf[ni], acc[mi][ni]);
    __builtin_amdgcn_s_setprio(0);
    if (t + 2 < NT) __asm__ volatile("s_waitcnt vmcnt(4)" ::: "memory");
    else            __asm__ volatile("s_waitcnt vmcnt(0)" ::: "memory");
    __builtin_amdgcn_s_barrier();
    sl = (sl == 2) ? 0 : sl + 1;
  }
#undef STAGE

  const int crow0 = (lane >> 4) * 4;
  float bv[4];
#pragma unroll
  for (int ni = 0; ni < 4; ni++) bv[ni] = b2f(bias[n0 + wn + ni * 16 + fr]);

  u16* W = smem + wave * 4096;
#pragma unroll
  for (int mi = 0; mi < 4; mi++) {
#pragma unroll
    for (int ni = 0; ni < 4; ni++) {
      f32x4 v = acc[mi][ni];
      const int colx = ni * 16 + fr;
      const int cl = colx & 7, ch = colx >> 3;
#pragma unroll
      for (int r = 0; r < 4; r++) {
        const int rowx = mi * 16 + crow0 + r;
        float f = v[r] + bv[ni]
                + b2f(rb[(size_t)ridx[m0 + wm + rowx] * rbs + n0 + wn + ni * 16 + fr]);
        if (relu) f = fmaxf(f, 0.0f);
        W[rowx * 64 + ((ch ^ (rowx & 7)) << 3) + cl] = f2b(f);
      }
    }
  }
  __asm__ volatile("s_waitcnt lgkmcnt(0)" ::: "memory");
#pragma unroll
  for (int p = 0; p < 8; p++) {
    const int rowx = p * 8 + (lane >> 3);
    const int pc = lane & 7;
    const int lc = pc ^ (rowx & 7);
    s16x8 val = *(const s16x8*)&W[rowx * 64 + pc * 8];
    *(s16x8*)&C[(size_t)(m0 + wm + rowx) * ldc + n0 + wn + lc * 8] = val;
  }
}

// ---------------- GEMM 256x256, BK=32, 3-slot ring, 1024 threads ----------------
// Round-6 EXACT body (no rb plumbing). Requires: M%256==0, N%256==0, K%32==0.
__global__ __launch_bounds__(1024) void gemm256b(
    const u16* __restrict__ A, const u16* __restrict__ Bt,
    const u16* __restrict__ bias, u16* __restrict__ C,
    int K, int ldc, int relu)
{
  __shared__ alignas(16) u16 smem[49152];  // 96KB: 3 slots x (A 8192 | B 8192) u16
  const int tid = threadIdx.x;
  const int wave = tid >> 6, lane = tid & 63;
  const int wr = wave >> 2, wc = wave & 3;
  const int m0 = blockIdx.x << 8, n0 = blockIdx.y << 8;

  const int srow = tid >> 2;
  const int kslot = tid & 3;
  const int sswz = (srow >> 1) & 3;
  const u16* gA = A  + (size_t)(m0 + srow) * K + (kslot ^ sswz) * 8;
  const u16* gB = Bt + (size_t)(n0 + srow) * K + (kslot ^ sswz) * 8;
  const int loff = tid * 8;                // u16; == srow*32 + kslot*8

  const int fr = lane & 15;
  const int fks = ((lane >> 4) ^ ((fr >> 1) & 3)) * 8;   // swizzled read slot
  const int aob = (wr * 64 + fr) * 32 + fks;             // + i*512
  const int bob = (wc * 64 + fr) * 32 + fks;             // + ni*512

  f32x4 acc[4][4] = {};
  const int NT = K >> 5;                   // BK=32 tiles

#define STAGE2(t, s) do { \
    const int o_ = (t) * 32; \
    u16* S_ = smem + (s) * 16384; \
    gld16(gA + o_, S_ + loff); gld16(gB + o_, S_ + 8192 + loff); \
  } while (0)

  STAGE2(0, 0);
  if (NT > 1) {
    STAGE2(1, 1);
    __asm__ volatile("s_waitcnt vmcnt(2)" ::: "memory");
  } else {
    __asm__ volatile("s_waitcnt vmcnt(0)" ::: "memory");
  }
  __builtin_amdgcn_s_barrier();

  int sl = 0;
  for (int t = 0; t < NT; t++) {
    if (t + 2 < NT) {
      const int sw = (sl + 2 >= 3) ? sl - 1 : sl + 2;
      STAGE2(t + 2, sw);
    }
    const u16* As = smem + sl * 16384;
    const u16* Bs = As + 8192;
    abvec af[4], bf[4];
#pragma unroll
    for (int i = 0; i < 4; i++)
      af[i] = *(const abvec*)&As[aob + i * 512];
#pragma unroll
    for (int i = 0; i < 4; i++)
      bf[i] = *(const abvec*)&Bs[bob + i * 512];
    __builtin_amdgcn_s_setprio(1);
#pragma unroll
    for (int mi = 0; mi < 4; mi++)
#pragma unroll
      for (int ni = 0; ni < 4; ni++)
        acc[mi][ni] = mfma_bf16(af[mi], bf[ni], acc[mi][ni]);
    __builtin_amdgcn_s_setprio(0);
    if (t + 2 < NT) __asm__ volatile("s_waitcnt vmcnt(2)" ::: "memory");
    else            __asm__ volatile("s_waitcnt vmcnt(0)" ::: "memory");
    __builtin_amdgcn_s_barrier();
    sl = (sl == 2) ? 0 : sl + 1;
  }
#undef STAGE2

  // epilogue: wave-private 64x32 half-tiles (4KB x 16 waves = 64KB), no barriers
  const int crow0 = (lane >> 4) * 4;
  float bv[4];
#pragma unroll
  for (int ni = 0; ni < 4; ni++) bv[ni] = b2f(bias[n0 + wc * 64 + ni * 16 + fr]);
  u16* W = smem + wave * 2048;             // 64 rows x 32 u16, col4 ^ (row&3) swizzle
#pragma unroll
  for (int h = 0; h < 2; h++) {
    if (h) __asm__ volatile("s_waitcnt lgkmcnt(0)" ::: "memory");
#pragma unroll
    for (int mi = 0; mi < 4; mi++) {
#pragma unroll
      for (int nh = 0; nh < 2; nh++) {
        const int ni = h * 2 + nh;
        f32x4 v = acc[mi][ni];
        const int colx = nh * 16 + fr;     // 0..31
        const int cl = colx & 7, ch = colx >> 3;   // ch 0..3
#pragma unroll
        for (int r = 0; r < 4; r++) {
          const int rowx = mi * 16 + crow0 + r;
          float f = v[r] + bv[ni];
          if (relu) f = fmaxf(f, 0.0f);
          W[rowx * 32 + ((ch ^ (rowx & 3)) << 3) + cl] = f2b(f);
        }
      }
    }
    __asm__ volatile("s_waitcnt lgkmcnt(0)" ::: "memory");
#pragma unroll
    for (int p = 0; p < 4; p++) {
      const int rowx = p * 16 + (lane >> 2);
      const int pc = lane & 3;
      const int lc = pc ^ (rowx & 3);
      s16x8 val = *(const s16x8*)&W[rowx * 32 + pc * 8];
      *(s16x8*)&C[(size_t)(m0 + wr * 64 + rowx) * ldc + n0 + wc * 64 + h * 32 + lc * 8] = val;
    }
  }
}

// ---------------- gemm256b_rb: separate clone with per-row bias (w0 K=32 only) ----------------
__global__ __launch_bounds__(1024) void gemm256b_rb(
    const u16* __restrict__ A, const u16* __restrict__ Bt,
    const u16* __restrict__ bias, u16* __restrict__ C,
    int K, int ldc, int relu,
    const u16* __restrict__ rb, const int* __restrict__ ridx, int rbs)
{
  __shared__ alignas(16) u16 smem[49152];
  const int tid = threadIdx.x;
  const int wave = tid >> 6, lane = tid & 63;
  const int wr = wave >> 2, wc = wave & 3;
  const int m0 = blockIdx.x << 8, n0 = blockIdx.y << 8;

  const int srow = tid >> 2;
  const int kslot = tid & 3;
  const int sswz = (srow >> 1) & 3;
  const u16* gA = A  + (size_t)(m0 + srow) * K + (kslot ^ sswz) * 8;
  const u16* gB = Bt + (size_t)(n0 + srow) * K + (kslot ^ sswz) * 8;
  const int loff = tid * 8;

  const int fr = lane & 15;
  const int fks = ((lane >> 4) ^ ((fr >> 1) & 3)) * 8;
  const int aob = (wr * 64 + fr) * 32 + fks;
  const int bob = (wc * 64 + fr) * 32 + fks;

  f32x4 acc[4][4] = {};
  const int NT = K >> 5;

#define STAGE2(t, s) do { \
    const int o_ = (t) * 32; \
    u16* S_ = smem + (s) * 16384; \
    gld16(gA + o_, S_ + loff); gld16(gB + o_, S_ + 8192 + loff); \
  } while (0)

  STAGE2(0, 0);
  if (NT > 1) {
    STAGE2(1, 1);
    __asm__ volatile("s_waitcnt vmcnt(2)" ::: "memory");
  } else {
    __asm__ volatile("s_waitcnt vmcnt(0)" ::: "memory");
  }
  __builtin_amdgcn_s_barrier();

  int sl = 0;
  for (int t = 0; t < NT; t++) {
    if (t + 2 < NT) {
      const int sw = (sl + 2 >= 3) ? sl - 1 : sl + 2;
      STAGE2(t + 2, sw);
    }
    const u16* As = smem + sl * 16384;
    const u16* Bs = As + 8192;
    abvec af[4], bf[4];
#pragma unroll
    for (int i = 0; i < 4; i++)
      af[i] = *(const abvec*)&As[aob + i * 512];
#pragma unroll
    for (int i = 0; i < 4; i++)
      bf[i] = *(const abvec*)&Bs[bob + i * 512];
    __builtin_amdgcn_s_setprio(1);
#pragma unroll
    for (int mi = 0; mi < 4; mi++)
#pragma unroll
      for (int ni = 0; ni < 4; ni++)
        acc[mi][ni] = mfma_bf16(af[mi], bf[ni], acc[mi][ni]);
    __builtin_amdgcn_s_setprio(0);
    if (t + 2 < NT) __asm__ volatile("s_waitcnt vmcnt(2)" ::: "memory");
    else            __asm__ volatile("s_waitcnt vmcnt(0)" ::: "memory");
    __builtin_amdgcn_s_barrier();
    sl = (sl == 2) ? 0 : sl + 1;
  }
#undef STAGE2

  const int crow0 = (lane >> 4) * 4;
  float bv[4];
#pragma unroll
  for (int ni = 0; ni < 4; ni++) bv[ni] = b2f(bias[n0 + wc * 64 + ni * 16 + fr]);
  u16* W = smem + wave * 2048;
#pragma unroll
  for (int h = 0; h < 2; h++) {
    if (h) __asm__ volatile("s_waitcnt lgkmcnt(0)" ::: "memory");
#pragma unroll
    for (int mi = 0; mi < 4; mi++) {
#pragma unroll
      for (int nh = 0; nh < 2; nh++) {
        const int ni = h * 2 + nh;
        f32x4 v = acc[mi][ni];
        const int colx = nh * 16 + fr;
        const int cl = colx & 7, ch = colx >> 3;
#pragma unroll
        for (int r = 0; r < 4; r++) {
          const int rowx = mi * 16 + crow0 + r;
          float f = v[r] + bv[ni]
                  + b2f(rb[(size_t)ridx[m0 + wr * 64 + rowx] * rbs + n0 + wc * 64 + ni * 16 + fr]);
          if (relu) f = fmaxf(f, 0.0f);
          W[rowx * 32 + ((ch ^ (rowx & 3)) << 3) + cl] = f2b(f);
        }
      }
    }
    __asm__ volatile("s_waitcnt lgkmcnt(0)" ::: "memory");
#pragma unroll
    for (int p = 0; p < 4; p++) {
      const int rowx = p * 16 + (lane >> 2);
      const int pc = lane & 3;
      const int lc = pc ^ (rowx & 3);
      s16x8 val = *(const s16x8*)&W[rowx * 32 + pc * 8];
      *(s16x8*)&C[(size_t)(m0 + wr * 64 + rowx) * ldc + n0 + wc * 64 + h * 32 + lc * 8] = val;
    }
  }
}

// -------- transpose + zero-pad + convert + optional K-permute; k0 = src row offset --------
__global__ __launch_bounds__(256) void transpose_pad(
    const void* __restrict__ src, u16* __restrict__ dst, int K, int N, int Kp,
    int perm, int k0, const int* __restrict__ flag)
{
  __shared__ u16 tile[32][33];
  const int f = *flag;
  const u16* s16p = (const u16*)src;
  const float* sfp = (const float*)src;
  const int kb = blockIdx.x * 32, nb = blockIdx.y * 32;
  const int tx = threadIdx.x & 31, ty = threadIdx.x >> 5;
#pragma unroll
  for (int i = 0; i < 32; i += 8) {
    int k = kb + ty + i, n = nb + tx;
    u16 v = 0;
    if (k < K && n < N)
      v = f ? s16p[(size_t)(k0 + k) * N + n] : f2b(sfp[(size_t)(k0 + k) * N + n]);
    tile[ty + i][tx] = v;
  }
  __syncthreads();
#pragma unroll
  for (int i = 0; i < 32; i += 8) {
    int n = nb + ty + i, k = kb + tx;
    if (n < N && k < Kp) {
      int nk = perm ? (k < 9 ? 512 + k : (k < 521 ? k - 9 : k)) : k;
      dst[(size_t)n * Kp + nk] = tile[tx][ty + i];
    }
  }
}

// -------- fused-tail: FUSEDT cols 1024..1055 = x-part of n1w0 (from N1W0T perm layout) --------
__global__ __launch_bounds__(256) void fuse_tail(
    const u16* __restrict__ n1w0t, u16* __restrict__ fused)
{
  const int idx = blockIdx.x * 256 + threadIdx.x;   // 512*32
  const int p = idx >> 5, t = idx & 31;
  fused[p * 1056 + 1024 + t] = n1w0t[p * 544 + 512 + t];  // cols 521..543 of N1W0T are 0
}

// -------- fused bias: FB[p] = n1b0[p] + sum_j e_bf[j] * n1w0_e[j][p] --------
__global__ __launch_bounds__(256) void fuse_bias(
    const u16* __restrict__ ebf, const u16* __restrict__ n1b0,
    const u16* __restrict__ n1w0e, u16* __restrict__ fb)
{
  const int p = blockIdx.x * 256 + threadIdx.x;     // 512
  float acc = b2f(n1b0[p]);
#pragma unroll 8
  for (int j = 0; j < 512; j++) acc += b2f(ebf[j]) * b2f(n1w0e[p * 512 + j]);
  fb[p] = f2b(acc);
}

// -------- rank-16 fold tables: UWB[g][n] = e_b0[n] + ur[g]·e_w0[19:275] --------
__global__ __launch_bounds__(256) void make_uwb(
    const void* __restrict__ w0, const u16* __restrict__ ur,
    const u16* __restrict__ eb0, u16* __restrict__ uwb,
    const int* __restrict__ flag)
{
  const int g = blockIdx.x;                // grid (16, 4)
  const int n = blockIdx.y * 256 + threadIdx.x;
  const int f = *flag;
  __shared__ u16 us[256];
  us[threadIdx.x] = ur[g * 256 + threadIdx.x];
  __syncthreads();
  float acc = b2f(eb0[n]);
  if (f) {
    const u16* wp = (const u16*)w0 + 19ull * 1024 + n;
#pragma unroll 8
    for (int j = 0; j < 256; j++) acc += b2f(us[j]) * b2f(wp[(size_t)j * 1024]);
  } else {
    const float* wp = (const float*)w0 + 19ull * 1024 + n;
#pragma unroll 8
    for (int j = 0; j < 256; j++) acc += b2f(us[j]) * wp[(size_t)j * 1024];
  }
  uwb[g * 1024 + n] = f2b(acc);
}

// -------- UW2[g][p] = n2b0[p] + ur[g]·n2w0[521:777] --------
__global__ __launch_bounds__(256) void make_uw2(
    const void* __restrict__ w, const u16* __restrict__ ur,
    const u16* __restrict__ b0, u16* __restrict__ uw2,
    const int* __restrict__ flag)
{
  const int g = blockIdx.x;                // grid (16, 2)
  const int p = blockIdx.y * 256 + threadIdx.x;
  const int f = *flag;
  __shared__ u16 us[256];
  us[threadIdx.x] = ur[g * 256 + threadIdx.x];
  __syncthreads();
  float acc = b2f(b0[p]);
  if (f) {
    const u16* wp = (const u16*)w + 521ull * 512 + p;
#pragma unroll 8
    for (int j = 0; j < 256; j++) acc += b2f(us[j]) * b2f(wp[(size_t)j * 512]);
  } else {
    const float* wp = (const float*)w + 521ull * 512 + p;
#pragma unroll 8
    for (int j = 0; j < 256; j++) acc += b2f(us[j]) * wp[(size_t)j * 512];
  }
  uw2[g * 512 + p] = f2b(acc);
}

// -------- dim_reduce K-split: grid (16 graphs, 8 k-tiles), partials into f32 --------
__global__ __launch_bounds__(256) void dim_reduce2(
    const u16* __restrict__ u, const void* __restrict__ w,
    float* __restrict__ uacc, const int* __restrict__ flag)
{
  const int g = blockIdx.x, kt = blockIdx.y, j = threadIdx.x;
  const int f = *flag;
  __shared__ u16 us[512];
  us[j] = u[g * 4096 + kt * 512 + j];
  us[256 + j] = u[g * 4096 + kt * 512 + 256 + j];
  __syncthreads();
  float acc = 0.0f;
  if (f) {
    const u16* wp = (const u16*)w + (size_t)(kt * 512) * 256 + j;
#pragma unroll 8
    for (int k = 0; k < 512; k++) acc += b2f(us[k]) * b2f(wp[(size_t)k * 256]);
  } else {
    const float* wp = (const float*)w + (size_t)(kt * 512) * 256 + j;
#pragma unroll 8
    for (int k = 0; k < 512; k++) acc += b2f(us[k]) * wp[(size_t)k * 256];
  }
  atomicAdd(&uacc[g * 256 + j], acc);
}

__global__ __launch_bounds__(256) void finish_ur(
    const float* __restrict__ uacc, const u16* __restrict__ bdr,
    u16* __restrict__ ur)
{
  const int i = blockIdx.x * 256 + threadIdx.x;  // 4096
  ur[i] = f2b(uacc[i] + b2f(bdr[i & 255]));
}

// -------- edge sort by row: count -> prefix -> perm --------
__global__ __launch_bounds__(256) void count_edges(
    const int* __restrict__ row, int* __restrict__ cnt)
{
  const int e = blockIdx.x * 256 + threadIdx.x;
  if (e < NE) atomicAdd(&cnt[row[e]], 1);
}

__global__ __launch_bounds__(256) void prefix_offs(
    const int* __restrict__ cnt, int* __restrict__ offs, int* __restrict__ cursor)
{
  __shared__ int part[256];
  __shared__ int base[256];
  const int t = threadIdx.x;
  int s = 0;
#pragma unroll
  for (int i = 0; i < 64; i++) s += cnt[t * 64 + i];
  part[t] = s;
  __syncthreads();
  if (t == 0) {
    int r = 0;
    for (int i = 0; i < 256; i++) { base[i] = r; r += part[i]; }
  }
  __syncthreads();
  int r = base[t];
#pragma unroll
  for (int i = 0; i < 64; i++) {
    const int n = t * 64 + i;
    offs[n] = r; cursor[n] = r; r += cnt[n];
  }
  if (t == 255) offs[16384] = r;   // == NE
}

__global__ __launch_bounds__(256) void build_perm(
    const int* __restrict__ row, int* __restrict__ cursor, int* __restrict__ eperm)
{
  const int e = blockIdx.x * 256 + threadIdx.x;
  const int pos = atomicAdd(&cursor[row[e]], 1);
  eperm[pos] = e;
}

// -------- edge input gather (sorted order), stride 32: [x_r(9)|x_c(9)|ea(1)|0] + bidx --------
__global__ __launch_bounds__(256) void build_ein2(
    const u16* __restrict__ x, const u16* __restrict__ ea,
    const int* __restrict__ row, const int* __restrict__ col,
    const int* __restrict__ batch, const int* __restrict__ eperm,
    u16* __restrict__ out, int* __restrict__ bidx, int e0)
{
  const int idx = blockIdx.x * 256 + threadIdx.x;   // echunk*4
  const int le = idx >> 2, g = idx & 3;
  const int c0 = g * 8;
  const int e = eperm[e0 + le];
  const int r = row[e];
  const int cl = col[e];
  if (g == 0) bidx[le] = batch[r];
  alignas(16) u16 v[8];
#pragma unroll
  for (int j = 0; j < 8; j++) {
    const int c = c0 + j;
    u16 t;
    if (c < 9)        t = x[r * 9 + c];
    else if (c < 18)  t = x[cl * 9 + (c - 9)];
    else if (c == 18) t = ea[e];
    else              t = 0;
    v[j] = t;
  }
  *(s16x8*)&out[(size_t)le * 32 + c0] = *(const s16x8*)v;
}

// -------- fill h-tail cols 1024..1055 with x[col] (stride 1056) --------
__global__ __launch_bounds__(256) void fill_h_tail(
    const u16* __restrict__ x, const int* __restrict__ col,
    const int* __restrict__ eperm, u16* __restrict__ out, int e0)
{
  const int idx = blockIdx.x * 256 + threadIdx.x;   // echunk*4
  const int le = idx >> 2, j8 = idx & 3;
  const int c0 = 1024 + j8 * 8;
  const int cl = col[eperm[e0 + le]];
  alignas(16) u16 v[8];
#pragma unroll
  for (int j = 0; j < 8; j++) {
    const int c = c0 + j;
    v[j] = (c < 1033) ? x[cl * 9 + (c - 1024)] : (u16)0;
  }
  *(s16x8*)&out[(size_t)le * 1056 + c0] = *(const s16x8*)v;
}

// -------- segment reduce (sorted rows; first-touch WRITES -> no AGG memset) --------
__global__ __launch_bounds__(256) void seg_reduce(
    const u16* __restrict__ h, const int* __restrict__ offs,
    float* __restrict__ agg, int e0, int echunk)
{
  const int wave = threadIdx.x >> 6, lane = threadIdx.x & 63;
  const int n = blockIdx.x * 4 + wave;
  int lo = offs[n], hi = offs[n + 1];
  const int first = (lo >= e0);            // segment's first edge is in this chunk
  lo = lo > e0 ? lo : e0;
  const int e1 = e0 + echunk;
  hi = hi < e1 ? hi : e1;
  if (lo >= hi) return;
  const int c0 = lane * 8;
  float acc[8] = {};
  for (int i = lo; i < hi; i++) {
    s16x8 v = *(const s16x8*)&h[(size_t)(i - e0) * 512 + c0];
#pragma unroll
    for (int j = 0; j < 8; j++) acc[j] += b2f((u16)v[j]);
  }
  float* ap = &agg[(size_t)n * 512 + c0];
  if (first) {
#pragma unroll
    for (int j = 0; j < 8; j++) ap[j] = acc[j];
  } else {
#pragma unroll
    for (int j = 0; j < 8; j++) ap[j] += acc[j];
  }
}

// -------- nin2 build: [agg/cnt(512) | x(9) | pad(23)] stride 544 (ur folded into UW2) --------
__global__ __launch_bounds__(256) void build_nin2(
    const u16* __restrict__ x, const float* __restrict__ agg,
    const int* __restrict__ cnt, u16* __restrict__ out, int n0)
{
  const int idx = blockIdx.x * 256 + threadIdx.x;   // nodch*68
  const int le = idx / 68, g = idx % 68;
  const int c0 = g * 8;
  const int n = n0 + le;
  alignas(16) u16 v[8];
  if (c0 < 512) {
    const int cn = cnt[n];
    if (cn == 0) {
#pragma unroll
      for (int j = 0; j < 8; j++) v[j] = 0;
    } else {
      const float den = (float)cn;
      const f32x4* ap = (const f32x4*)&agg[(size_t)n * 512 + c0];
      f32x4 a0 = ap[0], a1 = ap[1];
#pragma unroll
      for (int j = 0; j < 4; j++) { v[j] = f2b(a0[j] / den); v[4 + j] = f2b(a1[j] / den); }
    }
  } else {
#pragma unroll
    for (int j = 0; j < 8; j++) {
      const int c = c0 + j;
      v[j] = (c < 521) ? x[n * 9 + (c - 512)] : (u16)0;
    }
  }
  *(s16x8*)&out[(size_t)le * 544 + c0] = *(const s16x8*)v;
}

// -------- final: out[n0+n] = h[n,:] . w + b --------
__global__ __launch_bounds__(256) void final_dot(
    const u16* __restrict__ h, const u16* __restrict__ w,
    const u16* __restrict__ b, void* __restrict__ out, int n0,
    const int* __restrict__ flag)
{
  const int wave = threadIdx.x >> 6, lane = threadIdx.x & 63;
  const int n = blockIdx.x * 4 + wave;
  const u16* hp = h + (size_t)n * 512 + lane * 8;
  const u16* wp = w + lane * 8;
  float s = 0.0f;
#pragma unroll
  for (int i = 0; i < 8; i++) s += b2f(hp[i]) * b2f(wp[i]);
#pragma unroll
  for (int off = 32; off > 0; off >>= 1) s += __shfl_down(s, off, 64);
  if (lane == 0) {
    float r = s + b2f(b[0]);
    if (*flag) ((u16*)out)[n0 + n] = f2b(r);
    else       ((float*)out)[n0 + n] = r;
  }
}

// ---------------- workspace layout (static part) ----------------
constexpr size_t OFF_FLAG = 0;
constexpr size_t OFF_XC   = 64;
constexpr size_t OFF_EAC  = OFF_XC   + 147456ull * 2;
constexpr size_t OFF_UC   = OFF_EAC  + 131072ull * 2;
constexpr size_t OFF_BDR  = OFF_UC   + 65536ull * 2;
constexpr size_t OFF_EB0  = OFF_BDR  + 256ull * 2;
constexpr size_t OFF_EB1  = OFF_EB0  + 1024ull * 2;
constexpr size_t OFF_EB2  = OFF_EB1  + 1024ull * 2;
constexpr size_t OFF_EB3  = OFF_EB2  + 1024ull * 2;
constexpr size_t OFF_EBF  = OFF_EB3  + 1024ull * 2;
constexpr size_t OFF_N1B0 = OFF_EBF  + 512ull * 2;
constexpr size_t OFF_N1B1 = OFF_N1B0 + 512ull * 2;
constexpr size_t OFF_N2B0 = OFF_N1B1 + 512ull * 2;
constexpr size_t OFF_N2W1 = OFF_N2B0 + 512ull * 2;
constexpr size_t OFF_N2B1 = OFF_N2W1 + 512ull * 2;
constexpr size_t OFF_OFFS = (OFF_N2B1 + 64 + 63) & ~63ull;     // 16385 int
constexpr size_t OFF_CUR  = OFF_OFFS + 16388ull * 4;           // 16384 int
constexpr size_t OFF_UACC = OFF_CUR  + 16384ull * 4;           // 4096 f32
static_assert(OFF_UACC + 4096 * 4 < (1ull << 20), "params+small fit in 1MB");

constexpr size_t OFF_W0T  = 1ull << 20;                        // 1024x32
constexpr size_t OFF_W1T  = OFF_W0T  + 1024ull * 320 * 2;      // (slot kept sized for old 320)
constexpr size_t OFF_W2T  = OFF_W1T  + 1024ull * 1024 * 2;
constexpr size_t OFF_W3T  = OFF_W2T  + 1024ull * 1024 * 2;
constexpr size_t OFF_WFC  = OFF_W3T  + 1024ull * 1024 * 2;     // e_wf bf16 row-major 1024x512
constexpr size_t OFF_N1W0 = OFF_WFC  + 1024ull * 512 * 2;
constexpr size_t OFF_N1W1 = OFF_N1W0 + 512ull * 544 * 2;
constexpr size_t OFF_N2W0 = OFF_N1W1 + 512ull * 512 * 2;       // 512x544
constexpr size_t OFF_N1WE = OFF_N2W0 + 512ull * 800 * 2;
constexpr size_t OFF_FUSE = OFF_N1WE + 512ull * 512 * 2;       // fused Bt 512x1056
constexpr size_t OFF_FB   = OFF_FUSE + 512ull * 1056 * 2;      // fused bias 512
constexpr size_t OFF_ZB   = OFF_FB   + 512ull * 2;             // zero bias 1024
constexpr size_t OFF_UWB  = OFF_ZB   + 1024ull * 2;            // 16x1024 fold table
constexpr size_t OFF_UW2  = OFF_UWB  + 16384ull * 2;           // 16x512 fold table
constexpr size_t OFF_UR   = OFF_UW2  + 8192ull * 2;
constexpr size_t OFF_CNT  = OFF_UR   + 16ull * 256 * 2;
constexpr size_t OFF_AGG  = OFF_CNT  + 16384ull * 4;
constexpr size_t OFF_BUF0 = OFF_AGG  + 16384ull * 512 * 4;   // dynamic from here

extern "C" void kernel_launch(void* const* d_in, const int* in_sizes, int n_in,
                              void* d_out, int out_size, void* d_ws, size_t ws_size,
                              hipStream_t stream) {
  const void* x_r  = d_in[0];
  const void* ea_r = d_in[1];
  const void* u_r  = d_in[2];
  const int*  ei    = (const int*)d_in[3];
  const int*  batch = (const int*)d_in[4];
  const void* w_dr = d_in[5];
  const void* b_dr = d_in[6];
  const void* e_w0 = d_in[7];  const void* e_b0 = d_in[8];
  const void* e_w1 = d_in[9];  const void* e_b1 = d_in[10];
  const void* e_w2 = d_in[11]; const void* e_b2 = d_in[12];
  const void* e_w3 = d_in[13]; const void* e_b3 = d_in[14];
  const void* e_wf = d_in[15]; const void* e_bf = d_in[16];
  const void* n1w0 = d_in[17]; const void* n1b0 = d_in[18];
  const void* n1w1 = d_in[19]; const void* n1b1 = d_in[20];
  const void* n2w0 = d_in[21]; const void* n2b0 = d_in[22];
  const void* n2w1 = d_in[23]; const void* n2b1 = d_in[24];

  const int* row = ei;
  const int* col = ei + NE;

  char* ws = (char*)d_ws;
  int*   FLAG = (int*)(ws + OFF_FLAG);
  u16*   XC   = (u16*)(ws + OFF_XC);
  u16*   EAC  = (u16*)(ws + OFF_EAC);
  u16*   UC   = (u16*)(ws + OFF_UC);
  u16*   BDRC = (u16*)(ws + OFF_BDR);
  u16*   EB0C = (u16*)(ws + OFF_EB0);
  u16*   EB1C = (u16*)(ws + OFF_EB1);
  u16*   EB2C = (u16*)(ws + OFF_EB2);
  u16*   EB3C = (u16*)(ws + OFF_EB3);
  u16*   EBFC = (u16*)(ws + OFF_EBF);
  u16*   N1B0C= (u16*)(ws + OFF_N1B0);
  u16*   N1B1C= (u16*)(ws + OFF_N1B1);
  u16*   N2B0C= (u16*)(ws + OFF_N2B0);
  u16*   N2W1C= (u16*)(ws + OFF_N2W1);
  u16*   N2B1C= (u16*)(ws + OFF_N2B1);
  int*   OFFS = (int*)(ws + OFF_OFFS);
  int*   CUR  = (int*)(ws + OFF_CUR);
  float* UACC = (float*)(ws + OFF_UACC);
  u16*   W0T  = (u16*)(ws + OFF_W0T);
  u16*   W1T  = (u16*)(ws + OFF_W1T);
  u16*   W2T  = (u16*)(ws + OFF_W2T);
  u16*   W3T  = (u16*)(ws + OFF_W3T);
  u16*   WFC  = (u16*)(ws + OFF_WFC);
  u16*   N1W0T= (u16*)(ws + OFF_N1W0);
  u16*   N1W1T= (u16*)(ws + OFF_N1W1);
  u16*   N2W0T= (u16*)(ws + OFF_N2W0);
  u16*   N1WE = (u16*)(ws + OFF_N1WE);
  u16*   FUSED= (u16*)(ws + OFF_FUSE);
  u16*   FB   = (u16*)(ws + OFF_FB);
  u16*   ZB   = (u16*)(ws + OFF_ZB);
  u16*   UWB  = (u16*)(ws + OFF_UWB);
  u16*   UW2  = (u16*)(ws + OFF_UW2);
  u16*   UR   = (u16*)(ws + OFF_UR);
  int*   CNT  = (int*)(ws + OFF_CNT);
  float* AGG  = (float*)(ws + OFF_AGG);
  (void)in_sizes; (void)n_in; (void)out_size;

  // dynamic sizing: P,Q at 1056-u16 (2112B) row stride + perm ints + bidx ints
  int echunk = 16384;
  while (echunk > 2048 &&
         OFF_BUF0 + (size_t)echunk * 4228 + (size_t)NE * 4 > ws_size) echunk >>= 1;
  u16* P    = (u16*)(ws + OFF_BUF0);
  u16* Q    = (u16*)(ws + OFF_BUF0 + (size_t)echunk * 2112);
  int* EPRM = (int*)(ws + OFF_BUF0 + (size_t)echunk * 4224);
  int* BIDX = EPRM + NE;
  const int nchunks = NE / echunk;
  const int nodch = echunk < NN ? echunk : NN;
  const int nodchn = NN / nodch;

  detect_dtype<<<1, 256, 0, stream>>>((const u16*)x_r, FLAG);

  CvtJob jb;
  const void* srcs[14] = {x_r, ea_r, u_r, b_dr, e_b0, e_b1, e_b2, e_b3,
                          e_bf, n1b0, n1b1, n2b0, n2w1, n2b1};
  void* dsts[14] = {XC, EAC, UC, BDRC, EB0C, EB1C, EB2C, EB3C,
                    EBFC, N1B0C, N1B1C, N2B0C, N2W1C, N2B1C};
  const int ns[14] = {147456, 131072, 65536, 256, 1024, 1024, 1024, 1024,
                      512, 512, 512, 512, 512, 1};
  int tot = 0;
  for (int j = 0; j < 14; j++) { jb.src[j] = srcs[j]; jb.dst[j] = dsts[j]; jb.n[j] = ns[j]; tot += ns[j]; }
  cvt_all<<<(tot + 255) / 256, 256, 0, stream>>>(jb, FLAG);

  transpose_pad<<<dim3(1, 32),  256, 0, stream>>>(e_w0, W0T,   19, 1024, 32, 0, 0, FLAG);
  transpose_pad<<<dim3(32, 32), 256, 0, stream>>>(e_w1, W1T, 1024, 1024, 1024, 0, 0, FLAG);
  transpose_pad<<<dim3(32, 32), 256, 0, stream>>>(e_w2, W2T, 1024, 1024, 1024, 0, 0, FLAG);
  transpose_pad<<<dim3(32, 32), 256, 0, stream>>>(e_w3, W3T, 1024, 1024, 1024, 0, 0, FLAG);
  transpose_pad<<<dim3(17, 16), 256, 0, stream>>>(n1w0, N1W0T, 521, 512, 544, 1, 0, FLAG);
  transpose_pad<<<dim3(16, 16), 256, 0, stream>>>(n1w1, N1W1T, 512, 512, 512, 0, 0, FLAG);
  transpose_pad<<<dim3(17, 16), 256, 0, stream>>>(n2w0, N2W0T, 521, 512, 544, 1, 0, FLAG);
  // fused-weight prep: N1WE[p*512+j] = n1w0[9+j][p]; WFC = e_wf row-major bf16
  transpose_pad<<<dim3(16, 16), 256, 0, stream>>>(n1w0, N1WE, 512, 512, 512, 0, 9, FLAG);
  cvt_plain<<<2048, 256, 0, stream>>>(e_wf, WFC, 1024 * 512, FLAG);

  (void)hipMemsetAsync(UACC, 0, 4096ull * 4, stream);
  (void)hipMemsetAsync(CNT, 0, 16384ull * 4, stream);
  (void)hipMemsetAsync(ZB, 0, 2048, stream);

  // FUSED[p*1056 + k] = sum_j n1w0[9+j][p] * e_wf[k][j]  (k<1024); tail = x-part
  gemm_bt<<<dim3(4, 8), 256, 0, stream>>>(N1WE, WFC, ZB, FUSED, 512, 1024, 512, 1056, 0);
  fuse_tail<<<64, 256, 0, stream>>>(N1W0T, FUSED);
  fuse_bias<<<2, 256, 0, stream>>>(EBFC, N1B0C, N1WE, FB);

  dim_reduce2<<<dim3(NG, 8), 256, 0, stream>>>(UC, w_dr, UACC, FLAG);
  finish_ur<<<16, 256, 0, stream>>>(UACC, BDRC, UR);
  make_uwb<<<dim3(16, 4), 256, 0, stream>>>(e_w0, UR, EB0C, UWB, FLAG);
  make_uw2<<<dim3(16, 2), 256, 0, stream>>>(n2w0, UR, N2B0C, UW2, FLAG);

  count_edges<<<NE / 256, 256, 0, stream>>>(row, CNT);
  prefix_offs<<<1, 256, 0, stream>>>(CNT, OFFS, CUR);
  build_perm<<<NE / 256, 256, 0, stream>>>(row, CUR, EPRM);

  for (int c = 0; c < nchunks; c++) {
    const int e0 = c * echunk;
    build_ein2<<<echunk * 4 / 256, 256, 0, stream>>>(XC, EAC, row, col, batch, EPRM, P, BIDX, e0);
    gemm256b_rb<<<dim3(echunk / 256, 4), 1024, 0, stream>>>(P, W0T, ZB, Q, 32, 1024, 1,
                                                            UWB, BIDX, 1024);
    gemm256b<<<dim3(echunk / 256, 4), 1024, 0, stream>>>(Q, W1T, EB1C, P, 1024, 1024, 1);
    gemm256b<<<dim3(echunk / 256, 4), 1024, 0, stream>>>(P, W2T, EB2C, Q, 1024, 1024, 1);
    gemm256b<<<dim3(echunk / 256, 4), 1024, 0, stream>>>(Q, W3T, EB3C, P, 1024, 1056, 1);
    fill_h_tail<<<echunk * 4 / 256, 256, 0, stream>>>(XC, col, EPRM, P, e0);
    gemm_bt<<<dim3(echunk / 128, 4), 256, 0, stream>>>(P, FUSED, FB, Q, echunk, 512, 1056, 512, 1);
    gemm_bt<<<dim3(echunk / 128, 4), 256, 0, stream>>>(Q, N1W1T, N1B1C, P, echunk, 512, 512, 512, 1);
    seg_reduce<<<NN / 4, 256, 0, stream>>>(P, OFFS, AGG, e0, echunk);
  }

  for (int c = 0; c < nodchn; c++) {
    const int n0 = c * nodch;
    build_nin2<<<nodch * 68 / 256, 256, 0, stream>>>(XC, AGG, CNT, P, n0);
    gemm_bt_rb<<<dim3(nodch / 128, 4), 256, 0, stream>>>(P, N2W0T, ZB, Q, nodch, 512, 544, 512, 1,
                                                         UW2, batch + n0, 512);
    final_dot<<<nodch / 4, 256, 0, stream>>>(Q, N2W1C, N2B1C, d_out, n0, FLAG);
  }
}

// Round 9
// 1471.820 us; speedup vs baseline: 1.2126x; 1.1370x over previous
//
#include <hip/hip_runtime.h>
#include <type_traits>
#include <utility>
#include <cstdint>

typedef unsigned short u16;
typedef __attribute__((ext_vector_type(4))) float f32x4;
typedef __attribute__((ext_vector_type(8))) short s16x8;
typedef __attribute__((ext_vector_type(8))) __bf16 b16x8;

// ---- MFMA operand-type hedge: builtin takes either short8 or __bf16x8 ----
template <typename T, typename = void> struct MfmaTakes : std::false_type {};
template <typename T>
struct MfmaTakes<T, std::void_t<decltype(__builtin_amdgcn_mfma_f32_16x16x32_bf16(
    std::declval<T>(), std::declval<T>(), std::declval<f32x4>(), 0, 0, 0))>>
    : std::true_type {};
using abvec = std::conditional_t<MfmaTakes<s16x8>::value, s16x8, b16x8>;
static_assert(sizeof(abvec) == 16, "frag must be 4 VGPRs");

template <typename T>
__device__ __forceinline__ f32x4 mfma_bf16(T a, T b, f32x4 c) {
  return __builtin_amdgcn_mfma_f32_16x16x32_bf16(a, b, c, 0, 0, 0);
}

__device__ __forceinline__ float b2f(u16 v) {
  union { unsigned u; float f; } x; x.u = ((unsigned)v) << 16; return x.f;
}
__device__ __forceinline__ u16 f2b(float f) {
  union { float f; unsigned u; } x; x.f = f;
  unsigned r = x.u + 0x7fffu + ((x.u >> 16) & 1u);
  return (u16)(r >> 16);
}

__device__ __forceinline__ void gld16(const void* g, void* l) {
  auto gp = reinterpret_cast<const __attribute__((address_space(1))) unsigned int*>(
      reinterpret_cast<uintptr_t>(g));
  auto lp = reinterpret_cast<__attribute__((address_space(3))) unsigned int*>(
      reinterpret_cast<uintptr_t>(l));
  __builtin_amdgcn_global_load_lds(gp, lp, 16, 0, 0);
}

#define NN 16384
#define NE 131072
#define NG 16

// ---------------- dtype detect: bf16 vs f32 input buffers ----------------
__global__ void detect_dtype(const u16* __restrict__ x, int* __restrict__ flag) {
  __shared__ int cnt;
  if (threadIdx.x == 0) cnt = 0;
  __syncthreads();
  int local = 0;
#pragma unroll
  for (int i = 0; i < 8; i++) {
    u16 h = x[threadIdx.x * 8 + i];
    int e = (h >> 7) & 0xFF;
    if (h == 0 || (e >= 110 && e <= 134)) local++;
  }
  atomicAdd(&cnt, local);
  __syncthreads();
  if (threadIdx.x == 0) *flag = (cnt >= 1700) ? 1 : 0;
}

// ---------------- batched convert of tensors to bf16 ----------------
struct CvtJob {
  const void* src[14];
  void* dst[14];
  int n[14];
};

__global__ __launch_bounds__(256) void cvt_all(CvtJob jb, const int* __restrict__ flag) {
  const int idx = blockIdx.x * 256 + threadIdx.x;
  const int f = *flag;
  int off = 0;
#pragma unroll
  for (int j = 0; j < 14; j++) {
    const int nn = jb.n[j];
    if (idx < off + nn) {
      const int i = idx - off;
      u16 v = f ? ((const u16*)jb.src[j])[i]
                : f2b(((const float*)jb.src[j])[i]);
      ((u16*)jb.dst[j])[i] = v;
      return;
    }
    off += nn;
  }
}

// -------- plain convert (row-major, no transpose) --------
__global__ __launch_bounds__(256) void cvt_plain(
    const void* __restrict__ src, u16* __restrict__ dst, int n,
    const int* __restrict__ flag)
{
  const int i = blockIdx.x * 256 + threadIdx.x;
  if (i >= n) return;
  dst[i] = *flag ? ((const u16*)src)[i] : f2b(((const float*)src)[i]);
}

// ---------------- GEMM: 128x128, BK=32, 3-slot ring, counted vmcnt ----------------
// Round-6 EXACT body. Used for the FUSE-weight preamble + echunk<32768 fallback.
__global__ __launch_bounds__(256, 3) void gemm_bt(
    const u16* __restrict__ A, const u16* __restrict__ Bt,
    const u16* __restrict__ bias, u16* __restrict__ C,
    int M, int N, int K, int ldc, int relu)
{
  __shared__ alignas(16) u16 smem[24576];  // 48KB: 3 slots x (A 4096 | B 4096) u16
  const int tid = threadIdx.x;
  const int wave = tid >> 6, lane = tid & 63;
  const int m0 = blockIdx.x * 128, n0 = blockIdx.y * 128;

  const int srow = lane >> 2;              // 0..15
  const int kslot = lane & 3;              // 16B slot within row's 64B
  const int sswz = (srow >> 1) & 3;        // row-based XOR swizzle
  const u16* gA = A + (size_t)(m0 + wave * 32 + srow) * K + (kslot ^ sswz) * 8;
  const u16* gB = Bt + (size_t)(n0 + wave * 32 + srow) * K + (kslot ^ sswz) * 8;
  const int loff = (wave * 32 + srow) * 32 + kslot * 8;  // == wave*2048B + lane*16B

  const int wm = (wave >> 1) * 64;
  const int wn = (wave & 1) * 64;
  const int fr = lane & 15;
  const int fks = ((lane >> 4) ^ ((fr >> 1) & 3)) * 8;   // swizzled read slot

  f32x4 acc[4][4] = {};
  const int NT = K >> 5;                   // BK=32 tiles

#define STAGE(t, s) do { \
    const int o_ = (t) * 32; \
    u16* S_ = smem + (s) * 8192; \
    gld16(gA + o_, S_ + loff); gld16(gA + 16 * (size_t)K + o_, S_ + loff + 512); \
    gld16(gB + o_, S_ + 4096 + loff); gld16(gB + 16 * (size_t)K + o_, S_ + 4096 + loff + 512); \
  } while (0)

  STAGE(0, 0);
  if (NT > 1) {
    STAGE(1, 1);
    __asm__ volatile("s_waitcnt vmcnt(4)" ::: "memory");
  } else {
    __asm__ volatile("s_waitcnt vmcnt(0)" ::: "memory");
  }
  __builtin_amdgcn_s_barrier();

  int sl = 0;                              // slot of tile t
  for (int t = 0; t < NT; t++) {
    if (t + 2 < NT) {
      const int sw = (sl + 2 >= 3) ? sl - 1 : sl + 2;   // slot of tile t+2
      STAGE(t + 2, sw);
    }
    const u16* As = smem + sl * 8192;
    const u16* Bs = As + 4096;
    abvec af[4], bf[4];
#pragma unroll
    for (int i = 0; i < 4; i++)
      af[i] = *(const abvec*)&As[(wm + i * 16 + fr) * 32 + fks];
#pragma unroll
    for (int i = 0; i < 4; i++)
      bf[i] = *(const abvec*)&Bs[(wn + i * 16 + fr) * 32 + fks];
    __builtin_amdgcn_s_setprio(1);
#pragma unroll
    for (int mi = 0; mi < 4; mi++)
#pragma unroll
      for (int ni = 0; ni < 4; ni++)
        acc[mi][ni] = mfma_bf16(af[mi], bf[ni], acc[mi][ni]);
    __builtin_amdgcn_s_setprio(0);
    if (t + 2 < NT) __asm__ volatile("s_waitcnt vmcnt(4)" ::: "memory");
    else            __asm__ volatile("s_waitcnt vmcnt(0)" ::: "memory");
    __builtin_amdgcn_s_barrier();
    sl = (sl == 2) ? 0 : sl + 1;
  }
#undef STAGE

  const int crow0 = (lane >> 4) * 4;
  float bv[4];
#pragma unroll
  for (int ni = 0; ni < 4; ni++) bv[ni] = b2f(bias[n0 + wn + ni * 16 + fr]);

  u16* W = smem + wave * 4096;             // private 64x64, col8 ^ (row&7) swizzle
#pragma unroll
  for (int mi = 0; mi < 4; mi++) {
#pragma unroll
    for (int ni = 0; ni < 4; ni++) {
      f32x4 v = acc[mi][ni];
      const int colx = ni * 16 + fr;
      const int cl = colx & 7, ch = colx >> 3;
#pragma unroll
      for (int r = 0; r < 4; r++) {
        const int rowx = mi * 16 + crow0 + r;
        float f = v[r] + bv[ni];
        if (relu) f = fmaxf(f, 0.0f);
        W[rowx * 64 + ((ch ^ (rowx & 7)) << 3) + cl] = f2b(f);
      }
    }
  }
  __asm__ volatile("s_waitcnt lgkmcnt(0)" ::: "memory");
#pragma unroll
  for (int p = 0; p < 8; p++) {
    const int rowx = p * 8 + (lane >> 3);
    const int pc = lane & 7;
    const int lc = pc ^ (rowx & 7);
    s16x8 val = *(const s16x8*)&W[rowx * 64 + pc * 8];
    *(s16x8*)&C[(size_t)(m0 + wm + rowx) * ldc + n0 + wn + lc * 8] = val;
  }
}

// ---------------- gemm_bt_rb: separate clone with per-row bias (N2W0 only) ----------------
__global__ __launch_bounds__(256, 3) void gemm_bt_rb(
    const u16* __restrict__ A, const u16* __restrict__ Bt,
    const u16* __restrict__ bias, u16* __restrict__ C,
    int M, int N, int K, int ldc, int relu,
    const u16* __restrict__ rb, const int* __restrict__ ridx, int rbs)
{
  __shared__ alignas(16) u16 smem[24576];
  const int tid = threadIdx.x;
  const int wave = tid >> 6, lane = tid & 63;
  const int m0 = blockIdx.x * 128, n0 = blockIdx.y * 128;

  const int srow = lane >> 2;
  const int kslot = lane & 3;
  const int sswz = (srow >> 1) & 3;
  const u16* gA = A + (size_t)(m0 + wave * 32 + srow) * K + (kslot ^ sswz) * 8;
  const u16* gB = Bt + (size_t)(n0 + wave * 32 + srow) * K + (kslot ^ sswz) * 8;
  const int loff = (wave * 32 + srow) * 32 + kslot * 8;

  const int wm = (wave >> 1) * 64;
  const int wn = (wave & 1) * 64;
  const int fr = lane & 15;
  const int fks = ((lane >> 4) ^ ((fr >> 1) & 3)) * 8;

  f32x4 acc[4][4] = {};
  const int NT = K >> 5;

#define STAGE(t, s) do { \
    const int o_ = (t) * 32; \
    u16* S_ = smem + (s) * 8192; \
    gld16(gA + o_, S_ + loff); gld16(gA + 16 * (size_t)K + o_, S_ + loff + 512); \
    gld16(gB + o_, S_ + 4096 + loff); gld16(gB + 16 * (size_t)K + o_, S_ + 4096 + loff + 512); \
  } while (0)

  STAGE(0, 0);
  if (NT > 1) {
    STAGE(1, 1);
    __asm__ volatile("s_waitcnt vmcnt(4)" ::: "memory");
  } else {
    __asm__ volatile("s_waitcnt vmcnt(0)" ::: "memory");
  }
  __builtin_amdgcn_s_barrier();

  int sl = 0;
  for (int t = 0; t < NT; t++) {
    if (t + 2 < NT) {
      const int sw = (sl + 2 >= 3) ? sl - 1 : sl + 2;
      STAGE(t + 2, sw);
    }
    const u16* As = smem + sl * 8192;
    const u16* Bs = As + 4096;
    abvec af[4], bf[4];
#pragma unroll
    for (int i = 0; i < 4; i++)
      af[i] = *(const abvec*)&As[(wm + i * 16 + fr) * 32 + fks];
#pragma unroll
    for (int i = 0; i < 4; i++)
      bf[i] = *(const abvec*)&Bs[(wn + i * 16 + fr) * 32 + fks];
    __builtin_amdgcn_s_setprio(1);
#pragma unroll
    for (int mi = 0; mi < 4; mi++)
#pragma unroll
      for (int ni = 0; ni < 4; ni++)
        acc[mi][ni] = mfma_bf16(af[mi], bf[ni], acc[mi][ni]);
    __builtin_amdgcn_s_setprio(0);
    if (t + 2 < NT) __asm__ volatile("s_waitcnt vmcnt(4)" ::: "memory");
    else            __asm__ volatile("s_waitcnt vmcnt(0)" ::: "memory");
    __builtin_amdgcn_s_barrier();
    sl = (sl == 2) ? 0 : sl + 1;
  }
#undef STAGE

  const int crow0 = (lane >> 4) * 4;
  float bv[4];
#pragma unroll
  for (int ni = 0; ni < 4; ni++) bv[ni] = b2f(bias[n0 + wn + ni * 16 + fr]);

  u16* W = smem + wave * 4096;
#pragma unroll
  for (int mi = 0; mi < 4; mi++) {
#pragma unroll
    for (int ni = 0; ni < 4; ni++) {
      f32x4 v = acc[mi][ni];
      const int colx = ni * 16 + fr;
      const int cl = colx & 7, ch = colx >> 3;
#pragma unroll
      for (int r = 0; r < 4; r++) {
        const int rowx = mi * 16 + crow0 + r;
        float f = v[r] + bv[ni]
                + b2f(rb[(size_t)ridx[m0 + wm + rowx] * rbs + n0 + wn + ni * 16 + fr]);
        if (relu) f = fmaxf(f, 0.0f);
        W[rowx * 64 + ((ch ^ (rowx & 7)) << 3) + cl] = f2b(f);
      }
    }
  }
  __asm__ volatile("s_waitcnt lgkmcnt(0)" ::: "memory");
#pragma unroll
  for (int p = 0; p < 8; p++) {
    const int rowx = p * 8 + (lane >> 3);
    const int pc = lane & 7;
    const int lc = pc ^ (rowx & 7);
    s16x8 val = *(const s16x8*)&W[rowx * 64 + pc * 8];
    *(s16x8*)&C[(size_t)(m0 + wm + rowx) * ldc + n0 + wn + lc * 8] = val;
  }
}

// ---------------- GEMM 256x256, BK=32, 3-slot ring, 1024 threads ----------------
// Round-6 EXACT body. Now also used for N=512 shapes at M>=32768 (grid 128x2 = 1/CU).
__global__ __launch_bounds__(1024) void gemm256b(
    const u16* __restrict__ A, const u16* __restrict__ Bt,
    const u16* __restrict__ bias, u16* __restrict__ C,
    int K, int ldc, int relu)
{
  __shared__ alignas(16) u16 smem[49152];  // 96KB: 3 slots x (A 8192 | B 8192) u16
  const int tid = threadIdx.x;
  const int wave = tid >> 6, lane = tid & 63;
  const int wr = wave >> 2, wc = wave & 3;
  const int m0 = blockIdx.x << 8, n0 = blockIdx.y << 8;

  const int srow = tid >> 2;
  const int kslot = tid & 3;
  const int sswz = (srow >> 1) & 3;
  const u16* gA = A  + (size_t)(m0 + srow) * K + (kslot ^ sswz) * 8;
  const u16* gB = Bt + (size_t)(n0 + srow) * K + (kslot ^ sswz) * 8;
  const int loff = tid * 8;                // u16; == srow*32 + kslot*8

  const int fr = lane & 15;
  const int fks = ((lane >> 4) ^ ((fr >> 1) & 3)) * 8;   // swizzled read slot
  const int aob = (wr * 64 + fr) * 32 + fks;             // + i*512
  const int bob = (wc * 64 + fr) * 32 + fks;             // + ni*512

  f32x4 acc[4][4] = {};
  const int NT = K >> 5;                   // BK=32 tiles

#define STAGE2(t, s) do { \
    const int o_ = (t) * 32; \
    u16* S_ = smem + (s) * 16384; \
    gld16(gA + o_, S_ + loff); gld16(gB + o_, S_ + 8192 + loff); \
  } while (0)

  STAGE2(0, 0);
  if (NT > 1) {
    STAGE2(1, 1);
    __asm__ volatile("s_waitcnt vmcnt(2)" ::: "memory");
  } else {
    __asm__ volatile("s_waitcnt vmcnt(0)" ::: "memory");
  }
  __builtin_amdgcn_s_barrier();

  int sl = 0;
  for (int t = 0; t < NT; t++) {
    if (t + 2 < NT) {
      const int sw = (sl + 2 >= 3) ? sl - 1 : sl + 2;
      STAGE2(t + 2, sw);
    }
    const u16* As = smem + sl * 16384;
    const u16* Bs = As + 8192;
    abvec af[4], bf[4];
#pragma unroll
    for (int i = 0; i < 4; i++)
      af[i] = *(const abvec*)&As[aob + i * 512];
#pragma unroll
    for (int i = 0; i < 4; i++)
      bf[i] = *(const abvec*)&Bs[bob + i * 512];
    __builtin_amdgcn_s_setprio(1);
#pragma unroll
    for (int mi = 0; mi < 4; mi++)
#pragma unroll
      for (int ni = 0; ni < 4; ni++)
        acc[mi][ni] = mfma_bf16(af[mi], bf[ni], acc[mi][ni]);
    __builtin_amdgcn_s_setprio(0);
    if (t + 2 < NT) __asm__ volatile("s_waitcnt vmcnt(2)" ::: "memory");
    else            __asm__ volatile("s_waitcnt vmcnt(0)" ::: "memory");
    __builtin_amdgcn_s_barrier();
    sl = (sl == 2) ? 0 : sl + 1;
  }
#undef STAGE2

  // epilogue: wave-private 64x32 half-tiles (4KB x 16 waves = 64KB), no barriers
  const int crow0 = (lane >> 4) * 4;
  float bv[4];
#pragma unroll
  for (int ni = 0; ni < 4; ni++) bv[ni] = b2f(bias[n0 + wc * 64 + ni * 16 + fr]);
  u16* W = smem + wave * 2048;             // 64 rows x 32 u16, col4 ^ (row&3) swizzle
#pragma unroll
  for (int h = 0; h < 2; h++) {
    if (h) __asm__ volatile("s_waitcnt lgkmcnt(0)" ::: "memory");
#pragma unroll
    for (int mi = 0; mi < 4; mi++) {
#pragma unroll
      for (int nh = 0; nh < 2; nh++) {
        const int ni = h * 2 + nh;
        f32x4 v = acc[mi][ni];
        const int colx = nh * 16 + fr;     // 0..31
        const int cl = colx & 7, ch = colx >> 3;   // ch 0..3
#pragma unroll
        for (int r = 0; r < 4; r++) {
          const int rowx = mi * 16 + crow0 + r;
          float f = v[r] + bv[ni];
          if (relu) f = fmaxf(f, 0.0f);
          W[rowx * 32 + ((ch ^ (rowx & 3)) << 3) + cl] = f2b(f);
        }
      }
    }
    __asm__ volatile("s_waitcnt lgkmcnt(0)" ::: "memory");
#pragma unroll
    for (int p = 0; p < 4; p++) {
      const int rowx = p * 16 + (lane >> 2);
      const int pc = lane & 3;
      const int lc = pc ^ (rowx & 3);
      s16x8 val = *(const s16x8*)&W[rowx * 32 + pc * 8];
      *(s16x8*)&C[(size_t)(m0 + wr * 64 + rowx) * ldc + n0 + wc * 64 + h * 32 + lc * 8] = val;
    }
  }
}

// ---------------- gemm256c: 4-SLOT ring (128KB LDS, stage 3 ahead) — A/B arm ----------------
// Same proven body as gemm256b; only the ring depth and wait counts differ.
// In-flight at steady state: tiles t+1,t+2,t+3 (6 loads); vmcnt(4) waits t+1 only.
__global__ __launch_bounds__(1024) void gemm256c(
    const u16* __restrict__ A, const u16* __restrict__ Bt,
    const u16* __restrict__ bias, u16* __restrict__ C,
    int K, int ldc, int relu)
{
  __shared__ alignas(16) u16 smem[65536];  // 128KB: 4 slots x (A 8192 | B 8192) u16
  const int tid = threadIdx.x;
  const int wave = tid >> 6, lane = tid & 63;
  const int wr = wave >> 2, wc = wave & 3;
  const int m0 = blockIdx.x << 8, n0 = blockIdx.y << 8;

  const int srow = tid >> 2;
  const int kslot = tid & 3;
  const int sswz = (srow >> 1) & 3;
  const u16* gA = A  + (size_t)(m0 + srow) * K + (kslot ^ sswz) * 8;
  const u16* gB = Bt + (size_t)(n0 + srow) * K + (kslot ^ sswz) * 8;
  const int loff = tid * 8;

  const int fr = lane & 15;
  const int fks = ((lane >> 4) ^ ((fr >> 1) & 3)) * 8;
  const int aob = (wr * 64 + fr) * 32 + fks;
  const int bob = (wc * 64 + fr) * 32 + fks;

  f32x4 acc[4][4] = {};
  const int NT = K >> 5;

#define STAGE2(t, s) do { \
    const int o_ = (t) * 32; \
    u16* S_ = smem + (s) * 16384; \
    gld16(gA + o_, S_ + loff); gld16(gB + o_, S_ + 8192 + loff); \
  } while (0)

  STAGE2(0, 0);
  if (NT > 2) {
    STAGE2(1, 1); STAGE2(2, 2);
    __asm__ volatile("s_waitcnt vmcnt(4)" ::: "memory");
  } else if (NT > 1) {
    STAGE2(1, 1);
    __asm__ volatile("s_waitcnt vmcnt(2)" ::: "memory");
  } else {
    __asm__ volatile("s_waitcnt vmcnt(0)" ::: "memory");
  }
  __builtin_amdgcn_s_barrier();

  int sl = 0;
  for (int t = 0; t < NT; t++) {
    if (t + 3 < NT) STAGE2(t + 3, (sl + 3) & 3);   // dest slot == slot(t-1), freed last iter
    const u16* As = smem + sl * 16384;
    const u16* Bs = As + 8192;
    abvec af[4], bf[4];
#pragma unroll
    for (int i = 0; i < 4; i++)
      af[i] = *(const abvec*)&As[aob + i * 512];
#pragma unroll
    for (int i = 0; i < 4; i++)
      bf[i] = *(const abvec*)&Bs[bob + i * 512];
    __builtin_amdgcn_s_setprio(1);
#pragma unroll
    for (int mi = 0; mi < 4; mi++)
#pragma unroll
      for (int ni = 0; ni < 4; ni++)
        acc[mi][ni] = mfma_bf16(af[mi], bf[ni], acc[mi][ni]);
    __builtin_amdgcn_s_setprio(0);
    if (t + 3 < NT)      __asm__ volatile("s_waitcnt vmcnt(4)" ::: "memory");
    else if (t + 2 < NT) __asm__ volatile("s_waitcnt vmcnt(2)" ::: "memory");
    else                 __asm__ volatile("s_waitcnt vmcnt(0)" ::: "memory");
    __builtin_amdgcn_s_barrier();
    sl = (sl + 1) & 3;
  }
#undef STAGE2

  const int crow0 = (lane >> 4) * 4;
  float bv[4];
#pragma unroll
  for (int ni = 0; ni < 4; ni++) bv[ni] = b2f(bias[n0 + wc * 64 + ni * 16 + fr]);
  u16* W = smem + wave * 2048;
#pragma unroll
  for (int h = 0; h < 2; h++) {
    if (h) __asm__ volatile("s_waitcnt lgkmcnt(0)" ::: "memory");
#pragma unroll
    for (int mi = 0; mi < 4; mi++) {
#pragma unroll
      for (int nh = 0; nh < 2; nh++) {
        const int ni = h * 2 + nh;
        f32x4 v = acc[mi][ni];
        const int colx = nh * 16 + fr;
        const int cl = colx & 7, ch = colx >> 3;
#pragma unroll
        for (int r = 0; r < 4; r++) {
          const int rowx = mi * 16 + crow0 + r;
          float f = v[r] + bv[ni];
          if (relu) f = fmaxf(f, 0.0f);
          W[rowx * 32 + ((ch ^ (rowx & 3)) << 3) + cl] = f2b(f);
        }
      }
    }
    __asm__ volatile("s_waitcnt lgkmcnt(0)" ::: "memory");
#pragma unroll
    for (int p = 0; p < 4; p++) {
      const int rowx = p * 16 + (lane >> 2);
      const int pc = lane & 3;
      const int lc = pc ^ (rowx & 3);
      s16x8 val = *(const s16x8*)&W[rowx * 32 + pc * 8];
      *(s16x8*)&C[(size_t)(m0 + wr * 64 + rowx) * ldc + n0 + wc * 64 + h * 32 + lc * 8] = val;
    }
  }
}

// ---------------- gemm256b_rb: separate clone with per-row bias (w0 K=32 only) ----------------
__global__ __launch_bounds__(1024) void gemm256b_rb(
    const u16* __restrict__ A, const u16* __restrict__ Bt,
    const u16* __restrict__ bias, u16* __restrict__ C,
    int K, int ldc, int relu,
    const u16* __restrict__ rb, const int* __restrict__ ridx, int rbs)
{
  __shared__ alignas(16) u16 smem[49152];
  const int tid = threadIdx.x;
  const int wave = tid >> 6, lane = tid & 63;
  const int wr = wave >> 2, wc = wave & 3;
  const int m0 = blockIdx.x << 8, n0 = blockIdx.y << 8;

  const int srow = tid >> 2;
  const int kslot = tid & 3;
  const int sswz = (srow >> 1) & 3;
  const u16* gA = A  + (size_t)(m0 + srow) * K + (kslot ^ sswz) * 8;
  const u16* gB = Bt + (size_t)(n0 + srow) * K + (kslot ^ sswz) * 8;
  const int loff = tid * 8;

  const int fr = lane & 15;
  const int fks = ((lane >> 4) ^ ((fr >> 1) & 3)) * 8;
  const int aob = (wr * 64 + fr) * 32 + fks;
  const int bob = (wc * 64 + fr) * 32 + fks;

  f32x4 acc[4][4] = {};
  const int NT = K >> 5;

#define STAGE2(t, s) do { \
    const int o_ = (t) * 32; \
    u16* S_ = smem + (s) * 16384; \
    gld16(gA + o_, S_ + loff); gld16(gB + o_, S_ + 8192 + loff); \
  } while (0)

  STAGE2(0, 0);
  if (NT > 1) {
    STAGE2(1, 1);
    __asm__ volatile("s_waitcnt vmcnt(2)" ::: "memory");
  } else {
    __asm__ volatile("s_waitcnt vmcnt(0)" ::: "memory");
  }
  __builtin_amdgcn_s_barrier();

  int sl = 0;
  for (int t = 0; t < NT; t++) {
    if (t + 2 < NT) {
      const int sw = (sl + 2 >= 3) ? sl - 1 : sl + 2;
      STAGE2(t + 2, sw);
    }
    const u16* As = smem + sl * 16384;
    const u16* Bs = As + 8192;
    abvec af[4], bf[4];
#pragma unroll
    for (int i = 0; i < 4; i++)
      af[i] = *(const abvec*)&As[aob + i * 512];
#pragma unroll
    for (int i = 0; i < 4; i++)
      bf[i] = *(const abvec*)&Bs[bob + i * 512];
    __builtin_amdgcn_s_setprio(1);
#pragma unroll
    for (int mi = 0; mi < 4; mi++)
#pragma unroll
      for (int ni = 0; ni < 4; ni++)
        acc[mi][ni] = mfma_bf16(af[mi], bf[ni], acc[mi][ni]);
    __builtin_amdgcn_s_setprio(0);
    if (t + 2 < NT) __asm__ volatile("s_waitcnt vmcnt(2)" ::: "memory");
    else            __asm__ volatile("s_waitcnt vmcnt(0)" ::: "memory");
    __builtin_amdgcn_s_barrier();
    sl = (sl == 2) ? 0 : sl + 1;
  }
#undef STAGE2

  const int crow0 = (lane >> 4) * 4;
  float bv[4];
#pragma unroll
  for (int ni = 0; ni < 4; ni++) bv[ni] = b2f(bias[n0 + wc * 64 + ni * 16 + fr]);
  u16* W = smem + wave * 2048;
#pragma unroll
  for (int h = 0; h < 2; h++) {
    if (h) __asm__ volatile("s_waitcnt lgkmcnt(0)" ::: "memory");
#pragma unroll
    for (int mi = 0; mi < 4; mi++) {
#pragma unroll
      for (int nh = 0; nh < 2; nh++) {
        const int ni = h * 2 + nh;
        f32x4 v = acc[mi][ni];
        const int colx = nh * 16 + fr;
        const int cl = colx & 7, ch = colx >> 3;
#pragma unroll
        for (int r = 0; r < 4; r++) {
          const int rowx = mi * 16 + crow0 + r;
          float f = v[r] + bv[ni]
                  + b2f(rb[(size_t)ridx[m0 + wr * 64 + rowx] * rbs + n0 + wc * 64 + ni * 16 + fr]);
          if (relu) f = fmaxf(f, 0.0f);
          W[rowx * 32 + ((ch ^ (rowx & 3)) << 3) + cl] = f2b(f);
        }
      }
    }
    __asm__ volatile("s_waitcnt lgkmcnt(0)" ::: "memory");
#pragma unroll
    for (int p = 0; p < 4; p++) {
      const int rowx = p * 16 + (lane >> 2);
      const int pc = lane & 3;
      const int lc = pc ^ (rowx & 3);
      s16x8 val = *(const s16x8*)&W[rowx * 32 + pc * 8];
      *(s16x8*)&C[(size_t)(m0 + wr * 64 + rowx) * ldc + n0 + wc * 64 + h * 32 + lc * 8] = val;
    }
  }
}

// -------- transpose + zero-pad + convert + optional K-permute; k0 = src row offset --------
__global__ __launch_bounds__(256) void transpose_pad(
    const void* __restrict__ src, u16* __restrict__ dst, int K, int N, int Kp,
    int perm, int k0, const int* __restrict__ flag)
{
  __shared__ u16 tile[32][33];
  const int f = *flag;
  const u16* s16p = (const u16*)src;
  const float* sfp = (const float*)src;
  const int kb = blockIdx.x * 32, nb = blockIdx.y * 32;
  const int tx = threadIdx.x & 31, ty = threadIdx.x >> 5;
#pragma unroll
  for (int i = 0; i < 32; i += 8) {
    int k = kb + ty + i, n = nb + tx;
    u16 v = 0;
    if (k < K && n < N)
      v = f ? s16p[(size_t)(k0 + k) * N + n] : f2b(sfp[(size_t)(k0 + k) * N + n]);
    tile[ty + i][tx] = v;
  }
  __syncthreads();
#pragma unroll
  for (int i = 0; i < 32; i += 8) {
    int n = nb + ty + i, k = kb + tx;
    if (n < N && k < Kp) {
      int nk = perm ? (k < 9 ? 512 + k : (k < 521 ? k - 9 : k)) : k;
      dst[(size_t)n * Kp + nk] = tile[tx][ty + i];
    }
  }
}

// -------- fused-tail: FUSEDT cols 1024..1055 = x-part of n1w0 (from N1W0T perm layout) --------
__global__ __launch_bounds__(256) void fuse_tail(
    const u16* __restrict__ n1w0t, u16* __restrict__ fused)
{
  const int idx = blockIdx.x * 256 + threadIdx.x;   // 512*32
  const int p = idx >> 5, t = idx & 31;
  fused[p * 1056 + 1024 + t] = n1w0t[p * 544 + 512 + t];  // cols 521..543 of N1W0T are 0
}

// -------- fused bias: FB[p] = n1b0[p] + sum_j e_bf[j] * n1w0_e[j][p] --------
__global__ __launch_bounds__(256) void fuse_bias(
    const u16* __restrict__ ebf, const u16* __restrict__ n1b0,
    const u16* __restrict__ n1w0e, u16* __restrict__ fb)
{
  const int p = blockIdx.x * 256 + threadIdx.x;     // 512
  float acc = b2f(n1b0[p]);
#pragma unroll 8
  for (int j = 0; j < 512; j++) acc += b2f(ebf[j]) * b2f(n1w0e[p * 512 + j]);
  fb[p] = f2b(acc);
}

// -------- rank-16 fold tables: UWB[g][n] = e_b0[n] + ur[g]·e_w0[19:275] --------
__global__ __launch_bounds__(256) void make_uwb(
    const void* __restrict__ w0, const u16* __restrict__ ur,
    const u16* __restrict__ eb0, u16* __restrict__ uwb,
    const int* __restrict__ flag)
{
  const int g = blockIdx.x;                // grid (16, 4)
  const int n = blockIdx.y * 256 + threadIdx.x;
  const int f = *flag;
  __shared__ u16 us[256];
  us[threadIdx.x] = ur[g * 256 + threadIdx.x];
  __syncthreads();
  float acc = b2f(eb0[n]);
  if (f) {
    const u16* wp = (const u16*)w0 + 19ull * 1024 + n;
#pragma unroll 8
    for (int j = 0; j < 256; j++) acc += b2f(us[j]) * b2f(wp[(size_t)j * 1024]);
  } else {
    const float* wp = (const float*)w0 + 19ull * 1024 + n;
#pragma unroll 8
    for (int j = 0; j < 256; j++) acc += b2f(us[j]) * wp[(size_t)j * 1024];
  }
  uwb[g * 1024 + n] = f2b(acc);
}

// -------- UW2[g][p] = n2b0[p] + ur[g]·n2w0[521:777] --------
__global__ __launch_bounds__(256) void make_uw2(
    const void* __restrict__ w, const u16* __restrict__ ur,
    const u16* __restrict__ b0, u16* __restrict__ uw2,
    const int* __restrict__ flag)
{
  const int g = blockIdx.x;                // grid (16, 2)
  const int p = blockIdx.y * 256 + threadIdx.x;
  const int f = *flag;
  __shared__ u16 us[256];
  us[threadIdx.x] = ur[g * 256 + threadIdx.x];
  __syncthreads();
  float acc = b2f(b0[p]);
  if (f) {
    const u16* wp = (const u16*)w + 521ull * 512 + p;
#pragma unroll 8
    for (int j = 0; j < 256; j++) acc += b2f(us[j]) * b2f(wp[(size_t)j * 512]);
  } else {
    const float* wp = (const float*)w + 521ull * 512 + p;
#pragma unroll 8
    for (int j = 0; j < 256; j++) acc += b2f(us[j]) * wp[(size_t)j * 512];
  }
  uw2[g * 512 + p] = f2b(acc);
}

// -------- dim_reduce K-split: grid (16 graphs, 8 k-tiles), partials into f32 --------
__global__ __launch_bounds__(256) void dim_reduce2(
    const u16* __restrict__ u, const void* __restrict__ w,
    float* __restrict__ uacc, const int* __restrict__ flag)
{
  const int g = blockIdx.x, kt = blockIdx.y, j = threadIdx.x;
  const int f = *flag;
  __shared__ u16 us[512];
  us[j] = u[g * 4096 + kt * 512 + j];
  us[256 + j] = u[g * 4096 + kt * 512 + 256 + j];
  __syncthreads();
  float acc = 0.0f;
  if (f) {
    const u16* wp = (const u16*)w + (size_t)(kt * 512) * 256 + j;
#pragma unroll 8
    for (int k = 0; k < 512; k++) acc += b2f(us[k]) * b2f(wp[(size_t)k * 256]);
  } else {
    const float* wp = (const float*)w + (size_t)(kt * 512) * 256 + j;
#pragma unroll 8
    for (int k = 0; k < 512; k++) acc += b2f(us[k]) * wp[(size_t)k * 256];
  }
  atomicAdd(&uacc[g * 256 + j], acc);
}

__global__ __launch_bounds__(256) void finish_ur(
    const float* __restrict__ uacc, const u16* __restrict__ bdr,
    u16* __restrict__ ur)
{
  const int i = blockIdx.x * 256 + threadIdx.x;  // 4096
  ur[i] = f2b(uacc[i] + b2f(bdr[i & 255]));
}

// -------- edge sort by row: count -> prefix -> perm --------
__global__ __launch_bounds__(256) void count_edges(
    const int* __restrict__ row, int* __restrict__ cnt)
{
  const int e = blockIdx.x * 256 + threadIdx.x;
  if (e < NE) atomicAdd(&cnt[row[e]], 1);
}

__global__ __launch_bounds__(256) void prefix_offs(
    const int* __restrict__ cnt, int* __restrict__ offs, int* __restrict__ cursor)
{
  __shared__ int part[256];
  __shared__ int base[256];
  const int t = threadIdx.x;
  int s = 0;
#pragma unroll
  for (int i = 0; i < 64; i++) s += cnt[t * 64 + i];
  part[t] = s;
  __syncthreads();
  if (t == 0) {
    int r = 0;
    for (int i = 0; i < 256; i++) { base[i] = r; r += part[i]; }
  }
  __syncthreads();
  int r = base[t];
#pragma unroll
  for (int i = 0; i < 64; i++) {
    const int n = t * 64 + i;
    offs[n] = r; cursor[n] = r; r += cnt[n];
  }
  if (t == 255) offs[16384] = r;   // == NE
}

__global__ __launch_bounds__(256) void build_perm(
    const int* __restrict__ row, int* __restrict__ cursor, int* __restrict__ eperm)
{
  const int e = blockIdx.x * 256 + threadIdx.x;
  const int pos = atomicAdd(&cursor[row[e]], 1);
  eperm[pos] = e;
}

// -------- edge input gather (sorted order), stride 32: [x_r(9)|x_c(9)|ea(1)|0] + bidx --------
__global__ __launch_bounds__(256) void build_ein2(
    const u16* __restrict__ x, const u16* __restrict__ ea,
    const int* __restrict__ row, const int* __restrict__ col,
    const int* __restrict__ batch, const int* __restrict__ eperm,
    u16* __restrict__ out, int* __restrict__ bidx, int e0)
{
  const int idx = blockIdx.x * 256 + threadIdx.x;   // echunk*4
  const int le = idx >> 2, g = idx & 3;
  const int c0 = g * 8;
  const int e = eperm[e0 + le];
  const int r = row[e];
  const int cl = col[e];
  if (g == 0) bidx[le] = batch[r];
  alignas(16) u16 v[8];
#pragma unroll
  for (int j = 0; j < 8; j++) {
    const int c = c0 + j;
    u16 t;
    if (c < 9)        t = x[r * 9 + c];
    else if (c < 18)  t = x[cl * 9 + (c - 9)];
    else if (c == 18) t = ea[e];
    else              t = 0;
    v[j] = t;
  }
  *(s16x8*)&out[(size_t)le * 32 + c0] = *(const s16x8*)v;
}

// -------- fill h-tail cols 1024..1055 with x[col] (stride 1056) --------
__global__ __launch_bounds__(256) void fill_h_tail(
    const u16* __restrict__ x, const int* __restrict__ col,
    const int* __restrict__ eperm, u16* __restrict__ out, int e0)
{
  const int idx = blockIdx.x * 256 + threadIdx.x;   // echunk*4
  const int le = idx >> 2, j8 = idx & 3;
  const int c0 = 1024 + j8 * 8;
  const int cl = col[eperm[e0 + le]];
  alignas(16) u16 v[8];
#pragma unroll
  for (int j = 0; j < 8; j++) {
    const int c = c0 + j;
    v[j] = (c < 1033) ? x[cl * 9 + (c - 1024)] : (u16)0;
  }
  *(s16x8*)&out[(size_t)le * 1056 + c0] = *(const s16x8*)v;
}

// -------- segment reduce (sorted rows; first-touch WRITES -> no AGG memset) --------
__global__ __launch_bounds__(256) void seg_reduce(
    const u16* __restrict__ h, const int* __restrict__ offs,
    float* __restrict__ agg, int e0, int echunk)
{
  const int wave = threadIdx.x >> 6, lane = threadIdx.x & 63;
  const int n = blockIdx.x * 4 + wave;
  int lo = offs[n], hi = offs[n + 1];
  const int first = (lo >= e0);            // segment's first edge is in this chunk
  lo = lo > e0 ? lo : e0;
  const int e1 = e0 + echunk;
  hi = hi < e1 ? hi : e1;
  if (lo >= hi) return;
  const int c0 = lane * 8;
  float acc[8] = {};
  for (int i = lo; i < hi; i++) {
    s16x8 v = *(const s16x8*)&h[(size_t)(i - e0) * 512 + c0];
#pragma unroll
    for (int j = 0; j < 8; j++) acc[j] += b2f((u16)v[j]);
  }
  float* ap = &agg[(size_t)n * 512 + c0];
  if (first) {
#pragma unroll
    for (int j = 0; j < 8; j++) ap[j] = acc[j];
  } else {
#pragma unroll
    for (int j = 0; j < 8; j++) ap[j] += acc[j];
  }
}

// -------- nin2 build: [agg/cnt(512) | x(9) | pad(23)] stride 544 (ur folded into UW2) --------
__global__ __launch_bounds__(256) void build_nin2(
    const u16* __restrict__ x, const float* __restrict__ agg,
    const int* __restrict__ cnt, u16* __restrict__ out, int n0)
{
  const int idx = blockIdx.x * 256 + threadIdx.x;   // nodch*68
  const int le = idx / 68, g = idx % 68;
  const int c0 = g * 8;
  const int n = n0 + le;
  alignas(16) u16 v[8];
  if (c0 < 512) {
    const int cn = cnt[n];
    if (cn == 0) {
#pragma unroll
      for (int j = 0; j < 8; j++) v[j] = 0;
    } else {
      const float den = (float)cn;
      const f32x4* ap = (const f32x4*)&agg[(size_t)n * 512 + c0];
      f32x4 a0 = ap[0], a1 = ap[1];
#pragma unroll
      for (int j = 0; j < 4; j++) { v[j] = f2b(a0[j] / den); v[4 + j] = f2b(a1[j] / den); }
    }
  } else {
#pragma unroll
    for (int j = 0; j < 8; j++) {
      const int c = c0 + j;
      v[j] = (c < 521) ? x[n * 9 + (c - 512)] : (u16)0;
    }
  }
  *(s16x8*)&out[(size_t)le * 544 + c0] = *(const s16x8*)v;
}

// -------- final: out[n0+n] = h[n,:] . w + b --------
__global__ __launch_bounds__(256) void final_dot(
    const u16* __restrict__ h, const u16* __restrict__ w,
    const u16* __restrict__ b, void* __restrict__ out, int n0,
    const int* __restrict__ flag)
{
  const int wave = threadIdx.x >> 6, lane = threadIdx.x & 63;
  const int n = blockIdx.x * 4 + wave;
  const u16* hp = h + (size_t)n * 512 + lane * 8;
  const u16* wp = w + lane * 8;
  float s = 0.0f;
#pragma unroll
  for (int i = 0; i < 8; i++) s += b2f(hp[i]) * b2f(wp[i]);
#pragma unroll
  for (int off = 32; off > 0; off >>= 1) s += __shfl_down(s, off, 64);
  if (lane == 0) {
    float r = s + b2f(b[0]);
    if (*flag) ((u16*)out)[n0 + n] = f2b(r);
    else       ((float*)out)[n0 + n] = r;
  }
}

// ---------------- workspace layout (static part) ----------------
constexpr size_t OFF_FLAG = 0;
constexpr size_t OFF_XC   = 64;
constexpr size_t OFF_EAC  = OFF_XC   + 147456ull * 2;
constexpr size_t OFF_UC   = OFF_EAC  + 131072ull * 2;
constexpr size_t OFF_BDR  = OFF_UC   + 65536ull * 2;
constexpr size_t OFF_EB0  = OFF_BDR  + 256ull * 2;
constexpr size_t OFF_EB1  = OFF_EB0  + 1024ull * 2;
constexpr size_t OFF_EB2  = OFF_EB1  + 1024ull * 2;
constexpr size_t OFF_EB3  = OFF_EB2  + 1024ull * 2;
constexpr size_t OFF_EBF  = OFF_EB3  + 1024ull * 2;
constexpr size_t OFF_N1B0 = OFF_EBF  + 512ull * 2;
constexpr size_t OFF_N1B1 = OFF_N1B0 + 512ull * 2;
constexpr size_t OFF_N2B0 = OFF_N1B1 + 512ull * 2;
constexpr size_t OFF_N2W1 = OFF_N2B0 + 512ull * 2;
constexpr size_t OFF_N2B1 = OFF_N2W1 + 512ull * 2;
constexpr size_t OFF_OFFS = (OFF_N2B1 + 64 + 63) & ~63ull;     // 16385 int
constexpr size_t OFF_CUR  = OFF_OFFS + 16388ull * 4;           // 16384 int
constexpr size_t OFF_UACC = OFF_CUR  + 16384ull * 4;           // 4096 f32
static_assert(OFF_UACC + 4096 * 4 < (1ull << 20), "params+small fit in 1MB");

constexpr size_t OFF_W0T  = 1ull << 20;                        // 1024x32
constexpr size_t OFF_W1T  = OFF_W0T  + 1024ull * 320 * 2;      // (slot kept sized for old 320)
constexpr size_t OFF_W2T  = OFF_W1T  + 1024ull * 1024 * 2;
constexpr size_t OFF_W3T  = OFF_W2T  + 1024ull * 1024 * 2;
constexpr size_t OFF_WFC  = OFF_W3T  + 1024ull * 1024 * 2;     // e_wf bf16 row-major 1024x512
constexpr size_t OFF_N1W0 = OFF_WFC  + 1024ull * 512 * 2;
constexpr size_t OFF_N1W1 = OFF_N1W0 + 512ull * 544 * 2;
constexpr size_t OFF_N2W0 = OFF_N1W1 + 512ull * 512 * 2;       // 512x544
constexpr size_t OFF_N1WE = OFF_N2W0 + 512ull * 800 * 2;
constexpr size_t OFF_FUSE = OFF_N1WE + 512ull * 512 * 2;       // fused Bt 512x1056
constexpr size_t OFF_FB   = OFF_FUSE + 512ull * 1056 * 2;      // fused bias 512
constexpr size_t OFF_ZB   = OFF_FB   + 512ull * 2;             // zero bias 1024
constexpr size_t OFF_UWB  = OFF_ZB   + 1024ull * 2;            // 16x1024 fold table
constexpr size_t OFF_UW2  = OFF_UWB  + 16384ull * 2;           // 16x512 fold table
constexpr size_t OFF_UR   = OFF_UW2  + 8192ull * 2;
constexpr size_t OFF_CNT  = OFF_UR   + 16ull * 256 * 2;
constexpr size_t OFF_AGG  = OFF_CNT  + 16384ull * 4;
constexpr size_t OFF_BUF0 = OFF_AGG  + 16384ull * 512 * 4;   // dynamic from here (~45 MB)

extern "C" void kernel_launch(void* const* d_in, const int* in_sizes, int n_in,
                              void* d_out, int out_size, void* d_ws, size_t ws_size,
                              hipStream_t stream) {
  const void* x_r  = d_in[0];
  const void* ea_r = d_in[1];
  const void* u_r  = d_in[2];
  const int*  ei    = (const int*)d_in[3];
  const int*  batch = (const int*)d_in[4];
  const void* w_dr = d_in[5];
  const void* b_dr = d_in[6];
  const void* e_w0 = d_in[7];  const void* e_b0 = d_in[8];
  const void* e_w1 = d_in[9];  const void* e_b1 = d_in[10];
  const void* e_w2 = d_in[11]; const void* e_b2 = d_in[12];
  const void* e_w3 = d_in[13]; const void* e_b3 = d_in[14];
  const void* e_wf = d_in[15]; const void* e_bf = d_in[16];
  const void* n1w0 = d_in[17]; const void* n1b0 = d_in[18];
  const void* n1w1 = d_in[19]; const void* n1b1 = d_in[20];
  const void* n2w0 = d_in[21]; const void* n2b0 = d_in[22];
  const void* n2w1 = d_in[23]; const void* n2b1 = d_in[24];

  const int* row = ei;
  const int* col = ei + NE;

  char* ws = (char*)d_ws;
  int*   FLAG = (int*)(ws + OFF_FLAG);
  u16*   XC   = (u16*)(ws + OFF_XC);
  u16*   EAC  = (u16*)(ws + OFF_EAC);
  u16*   UC   = (u16*)(ws + OFF_UC);
  u16*   BDRC = (u16*)(ws + OFF_BDR);
  u16*   EB0C = (u16*)(ws + OFF_EB0);
  u16*   EB1C = (u16*)(ws + OFF_EB1);
  u16*   EB2C = (u16*)(ws + OFF_EB2);
  u16*   EB3C = (u16*)(ws + OFF_EB3);
  u16*   EBFC = (u16*)(ws + OFF_EBF);
  u16*   N1B0C= (u16*)(ws + OFF_N1B0);
  u16*   N1B1C= (u16*)(ws + OFF_N1B1);
  u16*   N2B0C= (u16*)(ws + OFF_N2B0);
  u16*   N2W1C= (u16*)(ws + OFF_N2W1);
  u16*   N2B1C= (u16*)(ws + OFF_N2B1);
  int*   OFFS = (int*)(ws + OFF_OFFS);
  int*   CUR  = (int*)(ws + OFF_CUR);
  float* UACC = (float*)(ws + OFF_UACC);
  u16*   W0T  = (u16*)(ws + OFF_W0T);
  u16*   W1T  = (u16*)(ws + OFF_W1T);
  u16*   W2T  = (u16*)(ws + OFF_W2T);
  u16*   W3T  = (u16*)(ws + OFF_W3T);
  u16*   WFC  = (u16*)(ws + OFF_WFC);
  u16*   N1W0T= (u16*)(ws + OFF_N1W0);
  u16*   N1W1T= (u16*)(ws + OFF_N1W1);
  u16*   N2W0T= (u16*)(ws + OFF_N2W0);
  u16*   N1WE = (u16*)(ws + OFF_N1WE);
  u16*   FUSED= (u16*)(ws + OFF_FUSE);
  u16*   FB   = (u16*)(ws + OFF_FB);
  u16*   ZB   = (u16*)(ws + OFF_ZB);
  u16*   UWB  = (u16*)(ws + OFF_UWB);
  u16*   UW2  = (u16*)(ws + OFF_UW2);
  u16*   UR   = (u16*)(ws + OFF_UR);
  int*   CNT  = (int*)(ws + OFF_CNT);
  float* AGG  = (float*)(ws + OFF_AGG);
  (void)in_sizes; (void)n_in; (void)out_size;

  // dynamic sizing: P,Q at 1056-u16 (2112B) row stride + perm ints + bidx ints.
  // Start at 32768 (4 chunks, ~184 MB total) — falls back by halving if ws too small.
  int echunk = 32768;
  while (echunk > 2048 &&
         OFF_BUF0 + (size_t)echunk * 4228 + (size_t)NE * 4 > ws_size) echunk >>= 1;
  u16* P    = (u16*)(ws + OFF_BUF0);
  u16* Q    = (u16*)(ws + OFF_BUF0 + (size_t)echunk * 2112);
  int* EPRM = (int*)(ws + OFF_BUF0 + (size_t)echunk * 4224);
  int* BIDX = EPRM + NE;
  const int nchunks = NE / echunk;
  const int nodch = echunk < NN ? echunk : NN;
  const int nodchn = NN / nodch;

  detect_dtype<<<1, 256, 0, stream>>>((const u16*)x_r, FLAG);

  CvtJob jb;
  const void* srcs[14] = {x_r, ea_r, u_r, b_dr, e_b0, e_b1, e_b2, e_b3,
                          e_bf, n1b0, n1b1, n2b0, n2w1, n2b1};
  void* dsts[14] = {XC, EAC, UC, BDRC, EB0C, EB1C, EB2C, EB3C,
                    EBFC, N1B0C, N1B1C, N2B0C, N2W1C, N2B1C};
  const int ns[14] = {147456, 131072, 65536, 256, 1024, 1024, 1024, 1024,
                      512, 512, 512, 512, 512, 1};
  int tot = 0;
  for (int j = 0; j < 14; j++) { jb.src[j] = srcs[j]; jb.dst[j] = dsts[j]; jb.n[j] = ns[j]; tot += ns[j]; }
  cvt_all<<<(tot + 255) / 256, 256, 0, stream>>>(jb, FLAG);

  transpose_pad<<<dim3(1, 32),  256, 0, stream>>>(e_w0, W0T,   19, 1024, 32, 0, 0, FLAG);
  transpose_pad<<<dim3(32, 32), 256, 0, stream>>>(e_w1, W1T, 1024, 1024, 1024, 0, 0, FLAG);
  transpose_pad<<<dim3(32, 32), 256, 0, stream>>>(e_w2, W2T, 1024, 1024, 1024, 0, 0, FLAG);
  transpose_pad<<<dim3(32, 32), 256, 0, stream>>>(e_w3, W3T, 1024, 1024, 1024, 0, 0, FLAG);
  transpose_pad<<<dim3(17, 16), 256, 0, stream>>>(n1w0, N1W0T, 521, 512, 544, 1, 0, FLAG);
  transpose_pad<<<dim3(16, 16), 256, 0, stream>>>(n1w1, N1W1T, 512, 512, 512, 0, 0, FLAG);
  transpose_pad<<<dim3(17, 16), 256, 0, stream>>>(n2w0, N2W0T, 521, 512, 544, 1, 0, FLAG);
  // fused-weight prep: N1WE[p*512+j] = n1w0[9+j][p]; WFC = e_wf row-major bf16
  transpose_pad<<<dim3(16, 16), 256, 0, stream>>>(n1w0, N1WE, 512, 512, 512, 0, 9, FLAG);
  cvt_plain<<<2048, 256, 0, stream>>>(e_wf, WFC, 1024 * 512, FLAG);

  (void)hipMemsetAsync(UACC, 0, 4096ull * 4, stream);
  (void)hipMemsetAsync(CNT, 0, 16384ull * 4, stream);
  (void)hipMemsetAsync(ZB, 0, 2048, stream);

  // FUSED[p*1056 + k] = sum_j n1w0[9+j][p] * e_wf[k][j]  (k<1024); tail = x-part
  gemm_bt<<<dim3(4, 8), 256, 0, stream>>>(N1WE, WFC, ZB, FUSED, 512, 1024, 512, 1056, 0);
  fuse_tail<<<64, 256, 0, stream>>>(N1W0T, FUSED);
  fuse_bias<<<2, 256, 0, stream>>>(EBFC, N1B0C, N1WE, FB);

  dim_reduce2<<<dim3(NG, 8), 256, 0, stream>>>(UC, w_dr, UACC, FLAG);
  finish_ur<<<16, 256, 0, stream>>>(UACC, BDRC, UR);
  make_uwb<<<dim3(16, 4), 256, 0, stream>>>(e_w0, UR, EB0C, UWB, FLAG);
  make_uw2<<<dim3(16, 2), 256, 0, stream>>>(n2w0, UR, N2B0C, UW2, FLAG);

  count_edges<<<NE / 256, 256, 0, stream>>>(row, CNT);
  prefix_offs<<<1, 256, 0, stream>>>(CNT, OFFS, CUR);
  build_perm<<<NE / 256, 256, 0, stream>>>(row, CUR, EPRM);

  for (int c = 0; c < nchunks; c++) {
    const int e0 = c * echunk;
    build_ein2<<<echunk * 4 / 256, 256, 0, stream>>>(XC, EAC, row, col, batch, EPRM, P, BIDX, e0);
    gemm256b_rb<<<dim3(echunk / 256, 4), 1024, 0, stream>>>(P, W0T, ZB, Q, 32, 1024, 1,
                                                            UWB, BIDX, 1024);
    if (c & 1) {
      gemm256b<<<dim3(echunk / 256, 4), 1024, 0, stream>>>(Q, W1T, EB1C, P, 1024, 1024, 1);
      gemm256b<<<dim3(echunk / 256, 4), 1024, 0, stream>>>(P, W2T, EB2C, Q, 1024, 1024, 1);
      gemm256b<<<dim3(echunk / 256, 4), 1024, 0, stream>>>(Q, W3T, EB3C, P, 1024, 1056, 1);
    } else {
      // A/B arm: 4-slot deeper-prefetch ring on identical shapes
      gemm256c<<<dim3(echunk / 256, 4), 1024, 0, stream>>>(Q, W1T, EB1C, P, 1024, 1024, 1);
      gemm256c<<<dim3(echunk / 256, 4), 1024, 0, stream>>>(P, W2T, EB2C, Q, 1024, 1024, 1);
      gemm256c<<<dim3(echunk / 256, 4), 1024, 0, stream>>>(Q, W3T, EB3C, P, 1024, 1056, 1);
    }
    fill_h_tail<<<echunk * 4 / 256, 256, 0, stream>>>(XC, col, EPRM, P, e0);
    if (echunk >= 32768) {
      // 256-tile for N=512 shapes: grid (128,2) = 256 blocks = exactly 1/CU
      gemm256b<<<dim3(echunk / 256, 2), 1024, 0, stream>>>(P, FUSED, FB, Q, 1056, 512, 1);
      gemm256b<<<dim3(echunk / 256, 2), 1024, 0, stream>>>(Q, N1W1T, N1B1C, P, 512, 512, 1);
    } else {
      gemm_bt<<<dim3(echunk / 128, 4), 256, 0, stream>>>(P, FUSED, FB, Q, echunk, 512, 1056, 512, 1);
      gemm_bt<<<dim3(echunk / 128, 4), 256, 0, stream>>>(Q, N1W1T, N1B1C, P, echunk, 512, 512, 512, 1);
    }
    seg_reduce<<<NN / 4, 256, 0, stream>>>(P, OFFS, AGG, e0, echunk);
  }

  for (int c = 0; c < nodchn; c++) {
    const int n0 = c * nodch;
    build_nin2<<<nodch * 68 / 256, 256, 0, stream>>>(XC, AGG, CNT, P, n0);
    gemm_bt_rb<<<dim3(nodch / 128, 4), 256, 0, stream>>>(P, N2W0T, ZB, Q, nodch, 512, 544, 512, 1,
                                                         UW2, batch + n0, 512);
    final_dot<<<nodch / 4, 256, 0, stream>>>(Q, N2W1C, N2B1C, d_out, n0, FLAG);
  }
}